// Round 3
// baseline (1971.319 us; speedup 1.0000x reference)
//
#include <hip/hip_runtime.h>

#define N_NODES 100000
#define N_EDGES 1600000
#define N_GRAPHS 64
#define DIM 128
#define BN_EPS 1e-5f

// ---------------- zero scratch ----------------
__global__ void k_zero(int* __restrict__ p, int n) {
    int i = blockIdx.x * blockDim.x + threadIdx.x;
    if (i < n) p[i] = 0;
}

// ---------------- degrees ----------------
__global__ void k_degrees(const int* __restrict__ src, const int* __restrict__ dst,
                          int* __restrict__ dego, int* __restrict__ degi) {
    int e = blockIdx.x * blockDim.x + threadIdx.x;
    if (e < N_EDGES) {
        atomicAdd(&dego[src[e]], 1);
        atomicAdd(&degi[dst[e]], 1);
    }
}

__global__ void k_norms(const int* __restrict__ dego, const int* __restrict__ degi,
                        float* __restrict__ ns, float* __restrict__ nd) {
    int i = blockIdx.x * blockDim.x + threadIdx.x;
    if (i < N_NODES) {
        ns[i] = rsqrtf(fmaxf((float)dego[i], 1.0f));
        nd[i] = rsqrtf(fmaxf((float)degi[i], 1.0f));
    }
}

// ---------------- scan (rowptr from deg_in) ----------------
#define SCAN_B 256
__global__ void k_scan1(const int* __restrict__ deg, int* __restrict__ rowptr,
                        int* __restrict__ partials) {
    __shared__ int s[SCAN_B];
    int t = threadIdx.x;
    int i = blockIdx.x * SCAN_B + t;
    int v = (i < N_NODES) ? deg[i] : 0;
    s[t] = v;
    __syncthreads();
    for (int off = 1; off < SCAN_B; off <<= 1) {
        int add = (t >= off) ? s[t - off] : 0;
        __syncthreads();
        s[t] += add;
        __syncthreads();
    }
    if (i < N_NODES) rowptr[i + 1] = s[t];
    if (t == SCAN_B - 1) partials[blockIdx.x] = s[t];
}

#define SCAN2_T 512
__global__ void k_scan2(int* __restrict__ partials, int* __restrict__ rowptr, int nb) {
    __shared__ int s[SCAN2_T];
    int t = threadIdx.x;
    int v = (t < nb) ? partials[t] : 0;
    s[t] = v;
    __syncthreads();
    for (int off = 1; off < SCAN2_T; off <<= 1) {
        int add = (t >= off) ? s[t - off] : 0;
        __syncthreads();
        s[t] += add;
        __syncthreads();
    }
    if (t < nb) partials[t] = s[t] - v;  // exclusive
    if (t == 0) rowptr[0] = 0;
}

__global__ void k_scan3(const int* __restrict__ partials, int* __restrict__ rowptr) {
    int i = blockIdx.x * SCAN_B + threadIdx.x;
    if (i < N_NODES) rowptr[i + 1] += partials[blockIdx.x];
}

// ---------------- CSR fill ----------------
__global__ void k_fill(const int* __restrict__ src, const int* __restrict__ dst,
                       const int* __restrict__ rowptr, int* __restrict__ cursor,
                       int* __restrict__ esrc) {
    int e = blockIdx.x * blockDim.x + threadIdx.x;
    if (e < N_EDGES) {
        int d = dst[e];
        int pos = rowptr[d] + atomicAdd(&cursor[d], 1);
        esrc[pos] = src[e];
    }
}

// ---------------- embedding gather * norm_src ----------------
__global__ void k_embed(const int* __restrict__ tokens, const float* __restrict__ embed,
                        const float* __restrict__ ns, float* __restrict__ hs) {
    int gid = blockIdx.x * blockDim.x + threadIdx.x;  // N*32
    int node = gid >> 5;
    int c4 = gid & 31;
    if (node >= N_NODES) return;
    int tok = tokens[node];
    float s = ns[node];
    float4 v = *(const float4*)(embed + (size_t)tok * DIM + c4 * 4);
    v.x *= s; v.y *= s; v.z *= s; v.w *= s;
    *(float4*)(hs + (size_t)node * DIM + c4 * 4) = v;
}

// ---------------- aggregation: one wave per node ----------------
__global__ void k_aggregate(const float* __restrict__ hs, const int* __restrict__ rowptr,
                            const int* __restrict__ esrc, const float* __restrict__ nd,
                            float* __restrict__ agg) {
    int wid = (blockIdx.x * blockDim.x + threadIdx.x) >> 6;
    int lane = threadIdx.x & 63;
    if (wid >= N_NODES) return;
    int beg = rowptr[wid], end = rowptr[wid + 1];
    float ax = 0.f, ay = 0.f;
    for (int e = beg; e < end; ++e) {
        int s = esrc[e];
        float2 v = *(const float2*)(hs + (size_t)s * DIM + lane * 2);
        ax += v.x; ay += v.y;
    }
    float n = nd[wid];
    float2 o; o.x = ax * n; o.y = ay * n;
    *(float2*)(agg + (size_t)wid * DIM + lane * 2) = o;
}

// ---------------- GEMM: y[N,128] = x[N,128] @ W[128,128] + bias ----------------
#define GEMM_ROWS 64
__global__ __launch_bounds__(256) void k_gemm(const float* __restrict__ x,
                                              const float* __restrict__ wf,
                                              const float* __restrict__ bias,
                                              float* __restrict__ y) {
    __shared__ float xs[GEMM_ROWS][DIM + 4];
    int row0 = blockIdx.x * GEMM_ROWS;
    // stage x tile
    for (int it = 0; it < 8; ++it) {
        int slot = threadIdx.x + it * 256;  // 0..2047 float4 slots
        int r = slot >> 5;
        int c4 = slot & 31;
        float4 v = make_float4(0.f, 0.f, 0.f, 0.f);
        if (row0 + r < N_NODES)
            v = *(const float4*)(x + (size_t)(row0 + r) * DIM + c4 * 4);
        *(float4*)&xs[r][c4 * 4] = v;
    }
    __syncthreads();

    int rowg = threadIdx.x >> 4;   // 0..15 (4 rows each)
    int colg = threadIdx.x & 15;   // 0..15 (8 cols each)
    const float* wp = wf + colg * 8;
    float acc[4][8];
#pragma unroll
    for (int j = 0; j < 4; ++j)
#pragma unroll
        for (int i = 0; i < 8; ++i) acc[j][i] = 0.f;

    for (int k0 = 0; k0 < DIM; k0 += 4) {
        float4 xv[4];
#pragma unroll
        for (int j = 0; j < 4; ++j)
            xv[j] = *(const float4*)&xs[rowg * 4 + j][k0];
#pragma unroll
        for (int kk = 0; kk < 4; ++kk) {
            float4 wa = *(const float4*)(wp + (size_t)(k0 + kk) * DIM);
            float4 wb = *(const float4*)(wp + (size_t)(k0 + kk) * DIM + 4);
#pragma unroll
            for (int j = 0; j < 4; ++j) {
                float xj = ((const float*)&xv[j])[kk];
                acc[j][0] += xj * wa.x; acc[j][1] += xj * wa.y;
                acc[j][2] += xj * wa.z; acc[j][3] += xj * wa.w;
                acc[j][4] += xj * wb.x; acc[j][5] += xj * wb.y;
                acc[j][6] += xj * wb.z; acc[j][7] += xj * wb.w;
            }
        }
    }
#pragma unroll
    for (int j = 0; j < 4; ++j) {
        int r = row0 + rowg * 4 + j;
        if (r < N_NODES) {
            float4 o0, o1;
            o0.x = acc[j][0] + bias[colg * 8 + 0];
            o0.y = acc[j][1] + bias[colg * 8 + 1];
            o0.z = acc[j][2] + bias[colg * 8 + 2];
            o0.w = acc[j][3] + bias[colg * 8 + 3];
            o1.x = acc[j][4] + bias[colg * 8 + 4];
            o1.y = acc[j][5] + bias[colg * 8 + 5];
            o1.z = acc[j][6] + bias[colg * 8 + 6];
            o1.w = acc[j][7] + bias[colg * 8 + 7];
            float* dst = y + (size_t)r * DIM + colg * 8;
            *(float4*)dst = o0;
            *(float4*)(dst + 4) = o1;
        }
    }
}

// ---------------- BN ----------------
__global__ void k_bnstats(const float* __restrict__ y, float* __restrict__ sum,
                          float* __restrict__ sumsq) {
    int col = threadIdx.x;  // 128 threads
    float s = 0.f, q = 0.f;
    for (int r = blockIdx.x; r < N_NODES; r += gridDim.x) {
        float v = y[(size_t)r * DIM + col];
        s += v; q += v * v;
    }
    atomicAdd(&sum[col], s);
    atomicAdd(&sumsq[col], q);
}

__global__ void k_bnfold(const float* __restrict__ sum, const float* __restrict__ sumsq,
                         const float* __restrict__ g, const float* __restrict__ be,
                         float* __restrict__ bna, float* __restrict__ bnc) {
    int c = threadIdx.x;  // 128
    float mu = sum[c] * (1.0f / N_NODES);
    float var = sumsq[c] * (1.0f / N_NODES) - mu * mu;
    float rstd = rsqrtf(var + BN_EPS);
    float a = g[c] * rstd;
    bna[c] = a;
    bnc[c] = be[c] - mu * a;
}

__global__ void k_bnapply(float* __restrict__ y, const float* __restrict__ bna,
                          const float* __restrict__ bnc, const float* __restrict__ scale) {
    int gid = blockIdx.x * blockDim.x + threadIdx.x;  // N*32
    int node = gid >> 5;
    int c4 = gid & 31;
    if (node >= N_NODES) return;
    float s = scale ? scale[node] : 1.0f;
    float4 v = *(float4*)(y + (size_t)node * DIM + c4 * 4);
    float4 a = *(const float4*)(bna + c4 * 4);
    float4 c = *(const float4*)(bnc + c4 * 4);
    v.x = fmaxf(v.x * a.x + c.x, 0.f) * s;
    v.y = fmaxf(v.y * a.y + c.y, 0.f) * s;
    v.z = fmaxf(v.z * a.z + c.z, 0.f) * s;
    v.w = fmaxf(v.w * a.w + c.w, 0.f) * s;
    *(float4*)(y + (size_t)node * DIM + c4 * 4) = v;
}

// ---------------- pooling ----------------
__global__ void k_poolcnt(const int* __restrict__ gids, int* __restrict__ cnt) {
    int i = blockIdx.x * blockDim.x + threadIdx.x;
    if (i < N_NODES) atomicAdd(&cnt[gids[i]], 1);
}

#define POOL_NODES 256
__global__ void k_poolsum(const float* __restrict__ h, const int* __restrict__ gids,
                          float* __restrict__ pool) {
    int col = threadIdx.x;  // 128
    int base = blockIdx.x * POOL_NODES;
    if (base >= N_NODES) return;
    int end = min(base + POOL_NODES, N_NODES);
    float acc = 0.f;
    int cur = gids[base];
    for (int n = base; n < end; ++n) {
        int g = gids[n];
        if (g != cur) {
            atomicAdd(&pool[(size_t)cur * DIM + col], acc);
            acc = 0.f;
            cur = g;
        }
        acc += h[(size_t)n * DIM + col];
    }
    atomicAdd(&pool[(size_t)cur * DIM + col], acc);
}

// ---------------- final FC (one block per graph) ----------------
__global__ void k_final(const float* __restrict__ pool, const int* __restrict__ cnt,
                        const float* __restrict__ fcW1, const float* __restrict__ fcb1,
                        const float* __restrict__ fcW2, const float* __restrict__ fcb2,
                        float* __restrict__ out) {
    __shared__ float hg[DIM];
    __shared__ float z[64];
    int g = blockIdx.x;
    int t = threadIdx.x;  // 128
    float cf = fmaxf((float)cnt[g], 1.0f);
    hg[t] = pool[(size_t)g * DIM + t] / cf;
    __syncthreads();
    if (t < 64) {
        float acc = fcb1[t];
        for (int k = 0; k < DIM; ++k)
            acc += hg[k] * fcW1[k * 64 + t];
        z[t] = fmaxf(acc, 0.f);
    }
    __syncthreads();
    if (t < 2) {
        float acc = fcb2[t];
        for (int k = 0; k < 64; ++k)
            acc += z[k] * fcW2[k * 2 + t];
        out[g * 2 + t] = acc;
    }
}

extern "C" void kernel_launch(void* const* d_in, const int* in_sizes, int n_in,
                              void* d_out, int out_size, void* d_ws, size_t ws_size,
                              hipStream_t stream) {
    const int* tokens = (const int*)d_in[0];
    const int* src = (const int*)d_in[1];
    const int* dst = (const int*)d_in[2];
    const int* gids = (const int*)d_in[3];
    const float* embed = (const float*)d_in[4];
    const float* W1 = (const float*)d_in[5];
    const float* b1 = (const float*)d_in[6];
    const float* g1 = (const float*)d_in[7];
    const float* be1 = (const float*)d_in[8];
    const float* W2 = (const float*)d_in[9];
    const float* b2 = (const float*)d_in[10];
    const float* g2 = (const float*)d_in[11];
    const float* be2 = (const float*)d_in[12];
    const float* W3 = (const float*)d_in[13];
    const float* b3 = (const float*)d_in[14];
    const float* g3 = (const float*)d_in[15];
    const float* be3 = (const float*)d_in[16];
    const float* fcW1 = (const float*)d_in[17];
    const float* fcb1 = (const float*)d_in[18];
    const float* fcW2 = (const float*)d_in[19];
    const float* fcb2 = (const float*)d_in[20];
    float* out = (float*)d_out;

    char* w = (char*)d_ws;
    auto alloc = [&](size_t bytes) {
        void* p = (void*)w;
        w += (bytes + 255) & ~(size_t)255;
        return p;
    };
    float* bufA = (float*)alloc((size_t)N_NODES * DIM * 4);
    float* bufB = (float*)alloc((size_t)N_NODES * DIM * 4);
    int* esrc = (int*)alloc((size_t)N_EDGES * 4);
    int* rowptr = (int*)alloc((size_t)(N_NODES + 1) * 4);
    float* ns = (float*)alloc((size_t)N_NODES * 4);
    float* nd = (float*)alloc((size_t)N_NODES * 4);
    float* bna = (float*)alloc(3 * DIM * 4);
    float* bnc = (float*)alloc(3 * DIM * 4);
    int* partials = (int*)alloc(1024 * 4);
    // zeroed region (contiguous)
    char* zstart = w;
    int* dego = (int*)alloc((size_t)N_NODES * 4);
    int* degi = (int*)alloc((size_t)N_NODES * 4);
    int* cursor = (int*)alloc((size_t)N_NODES * 4);
    float* bnsum = (float*)alloc(3 * DIM * 4);
    float* bnsq = (float*)alloc(3 * DIM * 4);
    float* pool = (float*)alloc((size_t)N_GRAPHS * DIM * 4);
    int* cnt = (int*)alloc((size_t)N_GRAPHS * 4);
    int zwords = (int)((size_t)(w - zstart) / 4);

    int nb_e = (N_EDGES + 255) / 256;
    int nb_n = (N_NODES + 255) / 256;
    int nb_scan = (N_NODES + SCAN_B - 1) / SCAN_B;

    k_zero<<<(zwords + 255) / 256, 256, 0, stream>>>((int*)zstart, zwords);
    k_degrees<<<nb_e, 256, 0, stream>>>(src, dst, dego, degi);
    k_norms<<<nb_n, 256, 0, stream>>>(dego, degi, ns, nd);
    k_scan1<<<nb_scan, SCAN_B, 0, stream>>>(degi, rowptr, partials);
    k_scan2<<<1, SCAN2_T, 0, stream>>>(partials, rowptr, nb_scan);
    k_scan3<<<nb_scan, SCAN_B, 0, stream>>>(partials, rowptr);
    k_fill<<<nb_e, 256, 0, stream>>>(src, dst, rowptr, cursor, esrc);
    k_embed<<<(N_NODES * 32 + 255) / 256, 256, 0, stream>>>(tokens, embed, ns, bufA);

    const float* W_l[3] = {W1, W2, W3};
    const float* bias_l[3] = {b1, b2, b3};
    const float* g_l[3] = {g1, g2, g3};
    const float* be_l[3] = {be1, be2, be3};
    int nb_agg = (N_NODES * 64 + 255) / 256;
    int nb_gemm = (N_NODES + GEMM_ROWS - 1) / GEMM_ROWS;
    int nb_bn = (N_NODES * 32 + 255) / 256;

    for (int l = 0; l < 3; ++l) {
        k_aggregate<<<nb_agg, 256, 0, stream>>>(bufA, rowptr, esrc, nd, bufB);
        k_gemm<<<nb_gemm, 256, 0, stream>>>(bufB, W_l[l], bias_l[l], bufA);
        k_bnstats<<<256, DIM, 0, stream>>>(bufA, bnsum + l * DIM, bnsq + l * DIM);
        k_bnfold<<<1, DIM, 0, stream>>>(bnsum + l * DIM, bnsq + l * DIM, g_l[l], be_l[l],
                                        bna + l * DIM, bnc + l * DIM);
        k_bnapply<<<nb_bn, 256, 0, stream>>>(bufA, bna + l * DIM, bnc + l * DIM,
                                             (l < 2) ? ns : (const float*)nullptr);
    }

    k_poolcnt<<<nb_n, 256, 0, stream>>>(gids, cnt);
    k_poolsum<<<(N_NODES + POOL_NODES - 1) / POOL_NODES, DIM, 0, stream>>>(bufA, gids, pool);
    k_final<<<N_GRAPHS, DIM, 0, stream>>>(pool, cnt, fcW1, fcb1, fcW2, fcb2, out);
}

// Round 4
// 1471.230 us; speedup vs baseline: 1.3399x; 1.3399x over previous
//
#include <hip/hip_runtime.h>

#define N_NODES 100000
#define N_EDGES 1600000
#define N_GRAPHS 64
#define DIM 128
#define BN_EPS 1e-5f

// ---------------- zero scratch ----------------
__global__ void k_zero(int* __restrict__ p, int n) {
    int i = blockIdx.x * blockDim.x + threadIdx.x;
    if (i < n) p[i] = 0;
}

// ---------------- degrees ----------------
__global__ void k_degrees(const int* __restrict__ src, const int* __restrict__ dst,
                          int* __restrict__ dego, int* __restrict__ degi) {
    int e = blockIdx.x * blockDim.x + threadIdx.x;
    if (e < N_EDGES) {
        atomicAdd(&dego[src[e]], 1);
        atomicAdd(&degi[dst[e]], 1);
    }
}

__global__ void k_norms(const int* __restrict__ dego, const int* __restrict__ degi,
                        float* __restrict__ ns, float* __restrict__ nd) {
    int i = blockIdx.x * blockDim.x + threadIdx.x;
    if (i < N_NODES) {
        ns[i] = rsqrtf(fmaxf((float)dego[i], 1.0f));
        nd[i] = rsqrtf(fmaxf((float)degi[i], 1.0f));
    }
}

// ---------------- scan (rowptr from deg_in) ----------------
#define SCAN_B 256
__global__ void k_scan1(const int* __restrict__ deg, int* __restrict__ rowptr,
                        int* __restrict__ partials) {
    __shared__ int s[SCAN_B];
    int t = threadIdx.x;
    int i = blockIdx.x * SCAN_B + t;
    int v = (i < N_NODES) ? deg[i] : 0;
    s[t] = v;
    __syncthreads();
    for (int off = 1; off < SCAN_B; off <<= 1) {
        int add = (t >= off) ? s[t - off] : 0;
        __syncthreads();
        s[t] += add;
        __syncthreads();
    }
    if (i < N_NODES) rowptr[i + 1] = s[t];
    if (t == SCAN_B - 1) partials[blockIdx.x] = s[t];
}

#define SCAN2_T 512
__global__ void k_scan2(int* __restrict__ partials, int* __restrict__ rowptr, int nb) {
    __shared__ int s[SCAN2_T];
    int t = threadIdx.x;
    int v = (t < nb) ? partials[t] : 0;
    s[t] = v;
    __syncthreads();
    for (int off = 1; off < SCAN2_T; off <<= 1) {
        int add = (t >= off) ? s[t - off] : 0;
        __syncthreads();
        s[t] += add;
        __syncthreads();
    }
    if (t < nb) partials[t] = s[t] - v;  // exclusive
    if (t == 0) rowptr[0] = 0;
}

__global__ void k_scan3(const int* __restrict__ partials, int* __restrict__ rowptr) {
    int i = blockIdx.x * SCAN_B + threadIdx.x;
    if (i < N_NODES) rowptr[i + 1] += partials[blockIdx.x];
}

// ---------------- CSR fill ----------------
__global__ void k_fill(const int* __restrict__ src, const int* __restrict__ dst,
                       const int* __restrict__ rowptr, int* __restrict__ cursor,
                       int* __restrict__ esrc) {
    int e = blockIdx.x * blockDim.x + threadIdx.x;
    if (e < N_EDGES) {
        int d = dst[e];
        int pos = rowptr[d] + atomicAdd(&cursor[d], 1);
        esrc[pos] = src[e];
    }
}

// ---------------- embedding gather * norm_src ----------------
__global__ void k_embed(const int* __restrict__ tokens, const float* __restrict__ embed,
                        const float* __restrict__ ns, float* __restrict__ hs) {
    int gid = blockIdx.x * blockDim.x + threadIdx.x;  // N*32
    int node = gid >> 5;
    int c4 = gid & 31;
    if (node >= N_NODES) return;
    int tok = tokens[node];
    float s = ns[node];
    float4 v = *(const float4*)(embed + (size_t)tok * DIM + c4 * 4);
    v.x *= s; v.y *= s; v.z *= s; v.w *= s;
    *(float4*)(hs + (size_t)node * DIM + c4 * 4) = v;
}

// ---------------- aggregation: one wave per node ----------------
__global__ void k_aggregate(const float* __restrict__ hs, const int* __restrict__ rowptr,
                            const int* __restrict__ esrc, const float* __restrict__ nd,
                            float* __restrict__ agg) {
    int wid = (blockIdx.x * blockDim.x + threadIdx.x) >> 6;
    int lane = threadIdx.x & 63;
    if (wid >= N_NODES) return;
    int beg = rowptr[wid], end = rowptr[wid + 1];
    float ax = 0.f, ay = 0.f;
    for (int e = beg; e < end; ++e) {
        int s = esrc[e];
        float2 v = *(const float2*)(hs + (size_t)s * DIM + lane * 2);
        ax += v.x; ay += v.y;
    }
    float n = nd[wid];
    float2 o; o.x = ax * n; o.y = ay * n;
    *(float2*)(agg + (size_t)wid * DIM + lane * 2) = o;
}

// ---------------- GEMM: y[N,128] = x[N,128] @ W[128,128] + bias ----------------
#define GEMM_ROWS 64
__global__ __launch_bounds__(256) void k_gemm(const float* __restrict__ x,
                                              const float* __restrict__ wf,
                                              const float* __restrict__ bias,
                                              float* __restrict__ y) {
    __shared__ float xs[GEMM_ROWS][DIM + 4];
    int row0 = blockIdx.x * GEMM_ROWS;
    // stage x tile
    for (int it = 0; it < 8; ++it) {
        int slot = threadIdx.x + it * 256;  // 0..2047 float4 slots
        int r = slot >> 5;
        int c4 = slot & 31;
        float4 v = make_float4(0.f, 0.f, 0.f, 0.f);
        if (row0 + r < N_NODES)
            v = *(const float4*)(x + (size_t)(row0 + r) * DIM + c4 * 4);
        *(float4*)&xs[r][c4 * 4] = v;
    }
    __syncthreads();

    int rowg = threadIdx.x >> 4;   // 0..15 (4 rows each)
    int colg = threadIdx.x & 15;   // 0..15 (8 cols each)
    const float* wp = wf + colg * 8;
    float acc[4][8];
#pragma unroll
    for (int j = 0; j < 4; ++j)
#pragma unroll
        for (int i = 0; i < 8; ++i) acc[j][i] = 0.f;

    for (int k0 = 0; k0 < DIM; k0 += 4) {
        float4 xv[4];
#pragma unroll
        for (int j = 0; j < 4; ++j)
            xv[j] = *(const float4*)&xs[rowg * 4 + j][k0];
#pragma unroll
        for (int kk = 0; kk < 4; ++kk) {
            float4 wa = *(const float4*)(wp + (size_t)(k0 + kk) * DIM);
            float4 wb = *(const float4*)(wp + (size_t)(k0 + kk) * DIM + 4);
#pragma unroll
            for (int j = 0; j < 4; ++j) {
                float xj = ((const float*)&xv[j])[kk];
                acc[j][0] += xj * wa.x; acc[j][1] += xj * wa.y;
                acc[j][2] += xj * wa.z; acc[j][3] += xj * wa.w;
                acc[j][4] += xj * wb.x; acc[j][5] += xj * wb.y;
                acc[j][6] += xj * wb.z; acc[j][7] += xj * wb.w;
            }
        }
    }
#pragma unroll
    for (int j = 0; j < 4; ++j) {
        int r = row0 + rowg * 4 + j;
        if (r < N_NODES) {
            float4 o0, o1;
            o0.x = acc[j][0] + bias[colg * 8 + 0];
            o0.y = acc[j][1] + bias[colg * 8 + 1];
            o0.z = acc[j][2] + bias[colg * 8 + 2];
            o0.w = acc[j][3] + bias[colg * 8 + 3];
            o1.x = acc[j][4] + bias[colg * 8 + 4];
            o1.y = acc[j][5] + bias[colg * 8 + 5];
            o1.z = acc[j][6] + bias[colg * 8 + 6];
            o1.w = acc[j][7] + bias[colg * 8 + 7];
            float* dst = y + (size_t)r * DIM + colg * 8;
            *(float4*)dst = o0;
            *(float4*)(dst + 4) = o1;
        }
    }
}

// ---------------- BN ----------------
__global__ void k_bnstats(const float* __restrict__ y, float* __restrict__ sum,
                          float* __restrict__ sumsq) {
    int col = threadIdx.x;  // 128 threads
    float s = 0.f, q = 0.f;
    for (int r = blockIdx.x; r < N_NODES; r += gridDim.x) {
        float v = y[(size_t)r * DIM + col];
        s += v; q += v * v;
    }
    atomicAdd(&sum[col], s);
    atomicAdd(&sumsq[col], q);
}

__global__ void k_bnfold(const float* __restrict__ sum, const float* __restrict__ sumsq,
                         const float* __restrict__ g, const float* __restrict__ be,
                         float* __restrict__ bna, float* __restrict__ bnc) {
    int c = threadIdx.x;  // 128
    float mu = sum[c] * (1.0f / N_NODES);
    float var = sumsq[c] * (1.0f / N_NODES) - mu * mu;
    float rstd = rsqrtf(var + BN_EPS);
    float a = g[c] * rstd;
    bna[c] = a;
    bnc[c] = be[c] - mu * a;
}

__global__ void k_bnapply(float* __restrict__ y, const float* __restrict__ bna,
                          const float* __restrict__ bnc, const float* __restrict__ scale) {
    int gid = blockIdx.x * blockDim.x + threadIdx.x;  // N*32
    int node = gid >> 5;
    int c4 = gid & 31;
    if (node >= N_NODES) return;
    float s = scale ? scale[node] : 1.0f;
    float4 v = *(float4*)(y + (size_t)node * DIM + c4 * 4);
    float4 a = *(const float4*)(bna + c4 * 4);
    float4 c = *(const float4*)(bnc + c4 * 4);
    v.x = fmaxf(v.x * a.x + c.x, 0.f) * s;
    v.y = fmaxf(v.y * a.y + c.y, 0.f) * s;
    v.z = fmaxf(v.z * a.z + c.z, 0.f) * s;
    v.w = fmaxf(v.w * a.w + c.w, 0.f) * s;
    *(float4*)(y + (size_t)node * DIM + c4 * 4) = v;
}

// ---------------- pooling: per-block LDS histogram (fixes atomic contention) ----------------
__global__ void k_poolcnt(const int* __restrict__ gids, int* __restrict__ cnt) {
    __shared__ int h[N_GRAPHS];
    if (threadIdx.x < N_GRAPHS) h[threadIdx.x] = 0;
    __syncthreads();
    int i = blockIdx.x * blockDim.x + threadIdx.x;
    if (i < N_NODES) atomicAdd(&h[gids[i]], 1);
    __syncthreads();
    if (threadIdx.x < N_GRAPHS) {
        int v = h[threadIdx.x];
        if (v) atomicAdd(&cnt[threadIdx.x], v);
    }
}

#define POOL_NODES 256
__global__ void k_poolsum(const float* __restrict__ h, const int* __restrict__ gids,
                          float* __restrict__ pool) {
    int col = threadIdx.x;  // 128
    int base = blockIdx.x * POOL_NODES;
    if (base >= N_NODES) return;
    int end = min(base + POOL_NODES, N_NODES);
    float acc = 0.f;
    int cur = gids[base];
    for (int n = base; n < end; ++n) {
        int g = gids[n];
        if (g != cur) {
            atomicAdd(&pool[(size_t)cur * DIM + col], acc);
            acc = 0.f;
            cur = g;
        }
        acc += h[(size_t)n * DIM + col];
    }
    atomicAdd(&pool[(size_t)cur * DIM + col], acc);
}

// ---------------- final FC (one block per graph) ----------------
__global__ void k_final(const float* __restrict__ pool, const int* __restrict__ cnt,
                        const float* __restrict__ fcW1, const float* __restrict__ fcb1,
                        const float* __restrict__ fcW2, const float* __restrict__ fcb2,
                        float* __restrict__ out) {
    __shared__ float hg[DIM];
    __shared__ float z[64];
    int g = blockIdx.x;
    int t = threadIdx.x;  // 128
    float cf = fmaxf((float)cnt[g], 1.0f);
    hg[t] = pool[(size_t)g * DIM + t] / cf;
    __syncthreads();
    if (t < 64) {
        float acc = fcb1[t];
        for (int k = 0; k < DIM; ++k)
            acc += hg[k] * fcW1[k * 64 + t];
        z[t] = fmaxf(acc, 0.f);
    }
    __syncthreads();
    if (t < 2) {
        float acc = fcb2[t];
        for (int k = 0; k < 64; ++k)
            acc += z[k] * fcW2[k * 2 + t];
        out[g * 2 + t] = acc;
    }
}

extern "C" void kernel_launch(void* const* d_in, const int* in_sizes, int n_in,
                              void* d_out, int out_size, void* d_ws, size_t ws_size,
                              hipStream_t stream) {
    const int* tokens = (const int*)d_in[0];
    const int* src = (const int*)d_in[1];
    const int* dst = (const int*)d_in[2];
    const int* gids = (const int*)d_in[3];
    const float* embed = (const float*)d_in[4];
    const float* W1 = (const float*)d_in[5];
    const float* b1 = (const float*)d_in[6];
    const float* g1 = (const float*)d_in[7];
    const float* be1 = (const float*)d_in[8];
    const float* W2 = (const float*)d_in[9];
    const float* b2 = (const float*)d_in[10];
    const float* g2 = (const float*)d_in[11];
    const float* be2 = (const float*)d_in[12];
    const float* W3 = (const float*)d_in[13];
    const float* b3 = (const float*)d_in[14];
    const float* g3 = (const float*)d_in[15];
    const float* be3 = (const float*)d_in[16];
    const float* fcW1 = (const float*)d_in[17];
    const float* fcb1 = (const float*)d_in[18];
    const float* fcW2 = (const float*)d_in[19];
    const float* fcb2 = (const float*)d_in[20];
    float* out = (float*)d_out;

    char* w = (char*)d_ws;
    auto alloc = [&](size_t bytes) {
        void* p = (void*)w;
        w += (bytes + 255) & ~(size_t)255;
        return p;
    };
    float* bufA = (float*)alloc((size_t)N_NODES * DIM * 4);
    float* bufB = (float*)alloc((size_t)N_NODES * DIM * 4);
    int* esrc = (int*)alloc((size_t)N_EDGES * 4);
    int* rowptr = (int*)alloc((size_t)(N_NODES + 1) * 4);
    float* ns = (float*)alloc((size_t)N_NODES * 4);
    float* nd = (float*)alloc((size_t)N_NODES * 4);
    float* bna = (float*)alloc(3 * DIM * 4);
    float* bnc = (float*)alloc(3 * DIM * 4);
    int* partials = (int*)alloc(1024 * 4);
    // zeroed region (contiguous)
    char* zstart = w;
    int* dego = (int*)alloc((size_t)N_NODES * 4);
    int* degi = (int*)alloc((size_t)N_NODES * 4);
    int* cursor = (int*)alloc((size_t)N_NODES * 4);
    float* bnsum = (float*)alloc(3 * DIM * 4);
    float* bnsq = (float*)alloc(3 * DIM * 4);
    float* pool = (float*)alloc((size_t)N_GRAPHS * DIM * 4);
    int* cnt = (int*)alloc((size_t)N_GRAPHS * 4);
    int zwords = (int)((size_t)(w - zstart) / 4);

    int nb_e = (N_EDGES + 255) / 256;
    int nb_n = (N_NODES + 255) / 256;
    int nb_scan = (N_NODES + SCAN_B - 1) / SCAN_B;

    k_zero<<<(zwords + 255) / 256, 256, 0, stream>>>((int*)zstart, zwords);
    k_degrees<<<nb_e, 256, 0, stream>>>(src, dst, dego, degi);
    k_norms<<<nb_n, 256, 0, stream>>>(dego, degi, ns, nd);
    k_scan1<<<nb_scan, SCAN_B, 0, stream>>>(degi, rowptr, partials);
    k_scan2<<<1, SCAN2_T, 0, stream>>>(partials, rowptr, nb_scan);
    k_scan3<<<nb_scan, SCAN_B, 0, stream>>>(partials, rowptr);
    k_fill<<<nb_e, 256, 0, stream>>>(src, dst, rowptr, cursor, esrc);
    k_embed<<<(N_NODES * 32 + 255) / 256, 256, 0, stream>>>(tokens, embed, ns, bufA);

    const float* W_l[3] = {W1, W2, W3};
    const float* bias_l[3] = {b1, b2, b3};
    const float* g_l[3] = {g1, g2, g3};
    const float* be_l[3] = {be1, be2, be3};
    int nb_agg = (N_NODES * 64 + 255) / 256;
    int nb_gemm = (N_NODES + GEMM_ROWS - 1) / GEMM_ROWS;
    int nb_bn = (N_NODES * 32 + 255) / 256;

    for (int l = 0; l < 3; ++l) {
        k_aggregate<<<nb_agg, 256, 0, stream>>>(bufA, rowptr, esrc, nd, bufB);
        k_gemm<<<nb_gemm, 256, 0, stream>>>(bufB, W_l[l], bias_l[l], bufA);
        k_bnstats<<<256, DIM, 0, stream>>>(bufA, bnsum + l * DIM, bnsq + l * DIM);
        k_bnfold<<<1, DIM, 0, stream>>>(bnsum + l * DIM, bnsq + l * DIM, g_l[l], be_l[l],
                                        bna + l * DIM, bnc + l * DIM);
        k_bnapply<<<nb_bn, 256, 0, stream>>>(bufA, bna + l * DIM, bnc + l * DIM,
                                             (l < 2) ? ns : (const float*)nullptr);
    }

    k_poolcnt<<<nb_n, 256, 0, stream>>>(gids, cnt);
    k_poolsum<<<(N_NODES + POOL_NODES - 1) / POOL_NODES, DIM, 0, stream>>>(bufA, gids, pool);
    k_final<<<N_GRAPHS, DIM, 0, stream>>>(pool, cnt, fcW1, fcb1, fcW2, fcb2, out);
}

// Round 5
// 1230.586 us; speedup vs baseline: 1.6019x; 1.1956x over previous
//
#include <hip/hip_runtime.h>

#define N_NODES 100000
#define N_EDGES 1600000
#define N_GRAPHS 64
#define DIM 128
#define BN_EPS 1e-5f

typedef unsigned short ushort_t;
typedef unsigned int uint_t;

__device__ __forceinline__ float bfl(uint_t u) {
    union { uint_t i; float f; } v; v.i = u << 16; return v.f;
}
__device__ __forceinline__ float bfh(uint_t u) {
    union { uint_t i; float f; } v; v.i = u & 0xffff0000u; return v.f;
}
__device__ __forceinline__ ushort_t f2bf(float f) {
    union { float f; uint_t i; } v; v.f = f;
    uint_t x = v.i;
    return (ushort_t)((x + 0x7fffu + ((x >> 16) & 1u)) >> 16);
}
__device__ __forceinline__ uint_t pack2(float lo, float hi) {
    return ((uint_t)f2bf(hi) << 16) | (uint_t)f2bf(lo);
}

// ---------------- zero scratch ----------------
__global__ void k_zero(int* __restrict__ p, int n) {
    int i = blockIdx.x * blockDim.x + threadIdx.x;
    if (i < n) p[i] = 0;
}

// ---------------- degrees ----------------
__global__ void k_degrees(const int* __restrict__ src, const int* __restrict__ dst,
                          int* __restrict__ dego, int* __restrict__ degi) {
    int e = blockIdx.x * blockDim.x + threadIdx.x;
    if (e < N_EDGES) {
        atomicAdd(&dego[src[e]], 1);
        atomicAdd(&degi[dst[e]], 1);
    }
}

__global__ void k_norms(const int* __restrict__ dego, const int* __restrict__ degi,
                        float* __restrict__ ns, float* __restrict__ nd) {
    int i = blockIdx.x * blockDim.x + threadIdx.x;
    if (i < N_NODES) {
        ns[i] = rsqrtf(fmaxf((float)dego[i], 1.0f));
        nd[i] = rsqrtf(fmaxf((float)degi[i], 1.0f));
    }
}

// ---------------- scan (rowptr from deg_in) ----------------
#define SCAN_B 256
__global__ void k_scan1(const int* __restrict__ deg, int* __restrict__ rowptr,
                        int* __restrict__ partials) {
    __shared__ int s[SCAN_B];
    int t = threadIdx.x;
    int i = blockIdx.x * SCAN_B + t;
    int v = (i < N_NODES) ? deg[i] : 0;
    s[t] = v;
    __syncthreads();
    for (int off = 1; off < SCAN_B; off <<= 1) {
        int add = (t >= off) ? s[t - off] : 0;
        __syncthreads();
        s[t] += add;
        __syncthreads();
    }
    if (i < N_NODES) rowptr[i + 1] = s[t];
    if (t == SCAN_B - 1) partials[blockIdx.x] = s[t];
}

#define SCAN2_T 512
__global__ void k_scan2(int* __restrict__ partials, int* __restrict__ rowptr, int nb) {
    __shared__ int s[SCAN2_T];
    int t = threadIdx.x;
    int v = (t < nb) ? partials[t] : 0;
    s[t] = v;
    __syncthreads();
    for (int off = 1; off < SCAN2_T; off <<= 1) {
        int add = (t >= off) ? s[t - off] : 0;
        __syncthreads();
        s[t] += add;
        __syncthreads();
    }
    if (t < nb) partials[t] = s[t] - v;  // exclusive
    if (t == 0) rowptr[0] = 0;
}

__global__ void k_scan3(const int* __restrict__ partials, int* __restrict__ rowptr) {
    int i = blockIdx.x * SCAN_B + threadIdx.x;
    if (i < N_NODES) rowptr[i + 1] += partials[blockIdx.x];
}

// ---------------- CSR fill ----------------
__global__ void k_fill(const int* __restrict__ src, const int* __restrict__ dst,
                       const int* __restrict__ rowptr, int* __restrict__ cursor,
                       int* __restrict__ esrc) {
    int e = blockIdx.x * blockDim.x + threadIdx.x;
    if (e < N_EDGES) {
        int d = dst[e];
        int pos = rowptr[d] + atomicAdd(&cursor[d], 1);
        esrc[pos] = src[e];
    }
}

// ---------------- embedding gather * norm_src -> bf16 ----------------
__global__ void k_embed(const int* __restrict__ tokens, const float* __restrict__ embed,
                        const float* __restrict__ ns, ushort_t* __restrict__ hs) {
    int gid = blockIdx.x * blockDim.x + threadIdx.x;  // N*16
    int node = gid >> 4;
    int sub = gid & 15;
    if (node >= N_NODES) return;
    int tok = tokens[node];
    float s = ns[node];
    const float* ep = embed + (size_t)tok * DIM + sub * 8;
    float4 a = *(const float4*)ep;
    float4 b = *(const float4*)(ep + 4);
    uint4 o;
    o.x = pack2(a.x * s, a.y * s);
    o.y = pack2(a.z * s, a.w * s);
    o.z = pack2(b.x * s, b.y * s);
    o.w = pack2(b.z * s, b.w * s);
    *(uint4*)(hs + (size_t)node * DIM + sub * 8) = o;
}

// ---------------- aggregation: one wave per node (bf16 rows, fp32 accum) ----------------
__global__ void k_aggregate(const ushort_t* __restrict__ hs, const int* __restrict__ rowptr,
                            const int* __restrict__ esrc, const float* __restrict__ nd,
                            ushort_t* __restrict__ agg) {
    int wid = (blockIdx.x * blockDim.x + threadIdx.x) >> 6;
    int lane = threadIdx.x & 63;
    if (wid >= N_NODES) return;
    int beg = rowptr[wid], end = rowptr[wid + 1];
    float ax = 0.f, ay = 0.f;
    for (int e = beg; e < end; ++e) {
        int s = esrc[e];
        uint_t u = *(const uint_t*)(hs + (size_t)s * DIM + lane * 2);
        ax += bfl(u);
        ay += bfh(u);
    }
    float n = nd[wid];
    *(uint_t*)(agg + (size_t)wid * DIM + lane * 2) = pack2(ax * n, ay * n);
}

// ---------------- GEMM + fused BN stats:
// y[N,128](bf16) = x[N,128](bf16) @ W[128,128](f32) + bias; atomically
// accumulates column sum / sumsq of y into bnsum/bnsq. ----------------
#define GEMM_ROWS 64
__global__ __launch_bounds__(256) void k_gemm(const ushort_t* __restrict__ x,
                                              const float* __restrict__ wf,
                                              const float* __restrict__ bias,
                                              ushort_t* __restrict__ y,
                                              float* __restrict__ bnsum,
                                              float* __restrict__ bnsq) {
    __shared__ float xs[GEMM_ROWS][DIM + 4];
    __shared__ float csum[DIM];
    __shared__ float csq[DIM];
    int row0 = blockIdx.x * GEMM_ROWS;
    // stage x tile (bf16 -> f32): 64x128 = 8192 vals, 256 thr x 8 vals x 4 iters
    for (int it = 0; it < 4; ++it) {
        int slot = threadIdx.x + it * 256;  // 0..1023
        int r = slot >> 4;
        int cs = (slot & 15) * 8;
        uint4 u = make_uint4(0u, 0u, 0u, 0u);
        if (row0 + r < N_NODES)
            u = *(const uint4*)(x + (size_t)(row0 + r) * DIM + cs);
        xs[r][cs + 0] = bfl(u.x); xs[r][cs + 1] = bfh(u.x);
        xs[r][cs + 2] = bfl(u.y); xs[r][cs + 3] = bfh(u.y);
        xs[r][cs + 4] = bfl(u.z); xs[r][cs + 5] = bfh(u.z);
        xs[r][cs + 6] = bfl(u.w); xs[r][cs + 7] = bfh(u.w);
    }
    if (threadIdx.x < DIM) { csum[threadIdx.x] = 0.f; csq[threadIdx.x] = 0.f; }
    __syncthreads();

    int rowg = threadIdx.x >> 4;   // 0..15 (4 rows each)
    int colg = threadIdx.x & 15;   // 0..15 (8 cols each)
    const float* wp = wf + colg * 8;
    float acc[4][8];
#pragma unroll
    for (int j = 0; j < 4; ++j)
#pragma unroll
        for (int i = 0; i < 8; ++i) acc[j][i] = 0.f;

    for (int k0 = 0; k0 < DIM; k0 += 4) {
        float4 xv[4];
#pragma unroll
        for (int j = 0; j < 4; ++j)
            xv[j] = *(const float4*)&xs[rowg * 4 + j][k0];
#pragma unroll
        for (int kk = 0; kk < 4; ++kk) {
            float4 wa = *(const float4*)(wp + (size_t)(k0 + kk) * DIM);
            float4 wb = *(const float4*)(wp + (size_t)(k0 + kk) * DIM + 4);
#pragma unroll
            for (int j = 0; j < 4; ++j) {
                float xj = ((const float*)&xv[j])[kk];
                acc[j][0] += xj * wa.x; acc[j][1] += xj * wa.y;
                acc[j][2] += xj * wa.z; acc[j][3] += xj * wa.w;
                acc[j][4] += xj * wb.x; acc[j][5] += xj * wb.y;
                acc[j][6] += xj * wb.z; acc[j][7] += xj * wb.w;
            }
        }
    }
    // add bias, accumulate stats, write y (bf16)
    float bb[8];
#pragma unroll
    for (int i = 0; i < 8; ++i) bb[i] = bias[colg * 8 + i];
    float ps[8], pq[8];
#pragma unroll
    for (int i = 0; i < 8; ++i) { ps[i] = 0.f; pq[i] = 0.f; }
#pragma unroll
    for (int j = 0; j < 4; ++j) {
        int r = row0 + rowg * 4 + j;
        if (r < N_NODES) {
            float v[8];
#pragma unroll
            for (int i = 0; i < 8; ++i) {
                v[i] = acc[j][i] + bb[i];
                ps[i] += v[i];
                pq[i] += v[i] * v[i];
            }
            uint4 o;
            o.x = pack2(v[0], v[1]); o.y = pack2(v[2], v[3]);
            o.z = pack2(v[4], v[5]); o.w = pack2(v[6], v[7]);
            *(uint4*)(y + (size_t)r * DIM + colg * 8) = o;
        }
    }
#pragma unroll
    for (int i = 0; i < 8; ++i) {
        atomicAdd(&csum[colg * 8 + i], ps[i]);
        atomicAdd(&csq[colg * 8 + i], pq[i]);
    }
    __syncthreads();
    if (threadIdx.x < DIM) {
        atomicAdd(&bnsum[threadIdx.x], csum[threadIdx.x]);
        atomicAdd(&bnsq[threadIdx.x], csq[threadIdx.x]);
    }
}

// ---------------- BN fold ----------------
__global__ void k_bnfold(const float* __restrict__ sum, const float* __restrict__ sumsq,
                         const float* __restrict__ g, const float* __restrict__ be,
                         float* __restrict__ bna, float* __restrict__ bnc) {
    int c = threadIdx.x;  // 128
    float mu = sum[c] * (1.0f / N_NODES);
    float var = sumsq[c] * (1.0f / N_NODES) - mu * mu;
    float rstd = rsqrtf(var + BN_EPS);
    float a = g[c] * rstd;
    bna[c] = a;
    bnc[c] = be[c] - mu * a;
}

// ---------------- BN apply + relu (+ norm_src prescale), bf16 in/out ----------------
__global__ void k_bnapply(const ushort_t* __restrict__ yin, ushort_t* __restrict__ xout,
                          const float* __restrict__ bna, const float* __restrict__ bnc,
                          const float* __restrict__ scale) {
    int gid = blockIdx.x * blockDim.x + threadIdx.x;  // N*16
    int node = gid >> 4;
    int sub = gid & 15;
    if (node >= N_NODES) return;
    float s = scale ? scale[node] : 1.0f;
    uint4 u = *(const uint4*)(yin + (size_t)node * DIM + sub * 8);
    float v[8] = {bfl(u.x), bfh(u.x), bfl(u.y), bfh(u.y),
                  bfl(u.z), bfh(u.z), bfl(u.w), bfh(u.w)};
    const float* a = bna + sub * 8;
    const float* c = bnc + sub * 8;
#pragma unroll
    for (int i = 0; i < 8; ++i) v[i] = fmaxf(v[i] * a[i] + c[i], 0.f) * s;
    uint4 o;
    o.x = pack2(v[0], v[1]); o.y = pack2(v[2], v[3]);
    o.z = pack2(v[4], v[5]); o.w = pack2(v[6], v[7]);
    *(uint4*)(xout + (size_t)node * DIM + sub * 8) = o;
}

// ---------------- pooling ----------------
__global__ void k_poolcnt(const int* __restrict__ gids, int* __restrict__ cnt) {
    __shared__ int h[N_GRAPHS];
    if (threadIdx.x < N_GRAPHS) h[threadIdx.x] = 0;
    __syncthreads();
    int i = blockIdx.x * blockDim.x + threadIdx.x;
    if (i < N_NODES) atomicAdd(&h[gids[i]], 1);
    __syncthreads();
    if (threadIdx.x < N_GRAPHS) {
        int v = h[threadIdx.x];
        if (v) atomicAdd(&cnt[threadIdx.x], v);
    }
}

#define POOL_NODES 256
__global__ void k_poolsum(const ushort_t* __restrict__ h, const int* __restrict__ gids,
                          float* __restrict__ pool) {
    int col = threadIdx.x;  // 128
    int base = blockIdx.x * POOL_NODES;
    if (base >= N_NODES) return;
    int end = min(base + POOL_NODES, N_NODES);
    float acc = 0.f;
    int cur = gids[base];
    for (int n = base; n < end; ++n) {
        int g = gids[n];
        if (g != cur) {
            atomicAdd(&pool[(size_t)cur * DIM + col], acc);
            acc = 0.f;
            cur = g;
        }
        uint_t u = *(const uint_t*)(h + (size_t)n * DIM + (col & ~1));
        acc += (col & 1) ? bfh(u) : bfl(u);
    }
    atomicAdd(&pool[(size_t)cur * DIM + col], acc);
}

// ---------------- final FC (one block per graph) ----------------
__global__ void k_final(const float* __restrict__ pool, const int* __restrict__ cnt,
                        const float* __restrict__ fcW1, const float* __restrict__ fcb1,
                        const float* __restrict__ fcW2, const float* __restrict__ fcb2,
                        float* __restrict__ out) {
    __shared__ float hg[DIM];
    __shared__ float z[64];
    int g = blockIdx.x;
    int t = threadIdx.x;  // 128
    float cf = fmaxf((float)cnt[g], 1.0f);
    hg[t] = pool[(size_t)g * DIM + t] / cf;
    __syncthreads();
    if (t < 64) {
        float acc = fcb1[t];
        for (int k = 0; k < DIM; ++k)
            acc += hg[k] * fcW1[k * 64 + t];
        z[t] = fmaxf(acc, 0.f);
    }
    __syncthreads();
    if (t < 2) {
        float acc = fcb2[t];
        for (int k = 0; k < 64; ++k)
            acc += z[k] * fcW2[k * 2 + t];
        out[g * 2 + t] = acc;
    }
}

extern "C" void kernel_launch(void* const* d_in, const int* in_sizes, int n_in,
                              void* d_out, int out_size, void* d_ws, size_t ws_size,
                              hipStream_t stream) {
    const int* tokens = (const int*)d_in[0];
    const int* src = (const int*)d_in[1];
    const int* dst = (const int*)d_in[2];
    const int* gids = (const int*)d_in[3];
    const float* embed = (const float*)d_in[4];
    const float* W1 = (const float*)d_in[5];
    const float* b1 = (const float*)d_in[6];
    const float* g1 = (const float*)d_in[7];
    const float* be1 = (const float*)d_in[8];
    const float* W2 = (const float*)d_in[9];
    const float* b2 = (const float*)d_in[10];
    const float* g2 = (const float*)d_in[11];
    const float* be2 = (const float*)d_in[12];
    const float* W3 = (const float*)d_in[13];
    const float* b3 = (const float*)d_in[14];
    const float* g3 = (const float*)d_in[15];
    const float* be3 = (const float*)d_in[16];
    const float* fcW1 = (const float*)d_in[17];
    const float* fcb1 = (const float*)d_in[18];
    const float* fcW2 = (const float*)d_in[19];
    const float* fcb2 = (const float*)d_in[20];
    float* out = (float*)d_out;

    char* w = (char*)d_ws;
    auto alloc = [&](size_t bytes) {
        void* p = (void*)w;
        w += (bytes + 255) & ~(size_t)255;
        return p;
    };
    // bf16 feature buffers (25.6 MB each)
    ushort_t* bufX = (ushort_t*)alloc((size_t)N_NODES * DIM * 2);   // aggregate input
    ushort_t* bufAgg = (ushort_t*)alloc((size_t)N_NODES * DIM * 2); // aggregate out / gemm x
    ushort_t* bufY = (ushort_t*)alloc((size_t)N_NODES * DIM * 2);   // gemm out (pre-BN)
    int* esrc = (int*)alloc((size_t)N_EDGES * 4);
    int* rowptr = (int*)alloc((size_t)(N_NODES + 1) * 4);
    float* ns = (float*)alloc((size_t)N_NODES * 4);
    float* nd = (float*)alloc((size_t)N_NODES * 4);
    float* bna = (float*)alloc(3 * DIM * 4);
    float* bnc = (float*)alloc(3 * DIM * 4);
    int* partials = (int*)alloc(1024 * 4);
    // zeroed region (contiguous)
    char* zstart = w;
    int* dego = (int*)alloc((size_t)N_NODES * 4);
    int* degi = (int*)alloc((size_t)N_NODES * 4);
    int* cursor = (int*)alloc((size_t)N_NODES * 4);
    float* bnsum = (float*)alloc(3 * DIM * 4);
    float* bnsq = (float*)alloc(3 * DIM * 4);
    float* pool = (float*)alloc((size_t)N_GRAPHS * DIM * 4);
    int* cnt = (int*)alloc((size_t)N_GRAPHS * 4);
    int zwords = (int)((size_t)(w - zstart) / 4);

    int nb_e = (N_EDGES + 255) / 256;
    int nb_n = (N_NODES + 255) / 256;
    int nb_scan = (N_NODES + SCAN_B - 1) / SCAN_B;

    k_zero<<<(zwords + 255) / 256, 256, 0, stream>>>((int*)zstart, zwords);
    k_degrees<<<nb_e, 256, 0, stream>>>(src, dst, dego, degi);
    k_norms<<<nb_n, 256, 0, stream>>>(dego, degi, ns, nd);
    k_scan1<<<nb_scan, SCAN_B, 0, stream>>>(degi, rowptr, partials);
    k_scan2<<<1, SCAN2_T, 0, stream>>>(partials, rowptr, nb_scan);
    k_scan3<<<nb_scan, SCAN_B, 0, stream>>>(partials, rowptr);
    k_fill<<<nb_e, 256, 0, stream>>>(src, dst, rowptr, cursor, esrc);
    k_embed<<<(N_NODES * 16 + 255) / 256, 256, 0, stream>>>(tokens, embed, ns, bufX);

    const float* W_l[3] = {W1, W2, W3};
    const float* bias_l[3] = {b1, b2, b3};
    const float* g_l[3] = {g1, g2, g3};
    const float* be_l[3] = {be1, be2, be3};
    int nb_agg = (N_NODES * 64 + 255) / 256;
    int nb_gemm = (N_NODES + GEMM_ROWS - 1) / GEMM_ROWS;
    int nb_el = (N_NODES * 16 + 255) / 256;

    for (int l = 0; l < 3; ++l) {
        k_aggregate<<<nb_agg, 256, 0, stream>>>(bufX, rowptr, esrc, nd, bufAgg);
        k_gemm<<<nb_gemm, 256, 0, stream>>>(bufAgg, W_l[l], bias_l[l], bufY,
                                            bnsum + l * DIM, bnsq + l * DIM);
        k_bnfold<<<1, DIM, 0, stream>>>(bnsum + l * DIM, bnsq + l * DIM, g_l[l], be_l[l],
                                        bna + l * DIM, bnc + l * DIM);
        k_bnapply<<<nb_el, 256, 0, stream>>>(bufY, bufX, bna + l * DIM, bnc + l * DIM,
                                             (l < 2) ? ns : (const float*)nullptr);
    }

    k_poolcnt<<<nb_n, 256, 0, stream>>>(gids, cnt);
    k_poolsum<<<(N_NODES + POOL_NODES - 1) / POOL_NODES, DIM, 0, stream>>>(bufX, gids, pool);
    k_final<<<N_GRAPHS, DIM, 0, stream>>>(pool, cnt, fcW1, fcb1, fcW2, fcb2, out);
}

// Round 6
// 1002.401 us; speedup vs baseline: 1.9666x; 1.2276x over previous
//
#include <hip/hip_runtime.h>

#define N_NODES 100000
#define N_EDGES 1600000
#define N_GRAPHS 64
#define DIM 128
#define BN_EPS 1e-5f

typedef unsigned short ushort_t;
typedef unsigned int uint_t;

__device__ __forceinline__ float bfl(uint_t u) {
    union { uint_t i; float f; } v; v.i = u << 16; return v.f;
}
__device__ __forceinline__ float bfh(uint_t u) {
    union { uint_t i; float f; } v; v.i = u & 0xffff0000u; return v.f;
}
__device__ __forceinline__ ushort_t f2bf(float f) {
    union { float f; uint_t i; } v; v.f = f;
    uint_t x = v.i;
    return (ushort_t)((x + 0x7fffu + ((x >> 16) & 1u)) >> 16);
}
__device__ __forceinline__ uint_t pack2(float lo, float hi) {
    return ((uint_t)f2bf(hi) << 16) | (uint_t)f2bf(lo);
}

// ---------------- zero scratch ----------------
__global__ void k_zero(int* __restrict__ p, int n) {
    int i = blockIdx.x * blockDim.x + threadIdx.x;
    if (i < n) p[i] = 0;
}

// ---------------- degrees ----------------
__global__ void k_degrees(const int* __restrict__ src, const int* __restrict__ dst,
                          int* __restrict__ dego, int* __restrict__ degi) {
    int e = blockIdx.x * blockDim.x + threadIdx.x;
    if (e < N_EDGES) {
        atomicAdd(&dego[src[e]], 1);
        atomicAdd(&degi[dst[e]], 1);
    }
}

__global__ void k_norms(const int* __restrict__ dego, const int* __restrict__ degi,
                        float* __restrict__ ns, float* __restrict__ nd) {
    int i = blockIdx.x * blockDim.x + threadIdx.x;
    if (i < N_NODES) {
        ns[i] = rsqrtf(fmaxf((float)dego[i], 1.0f));
        nd[i] = rsqrtf(fmaxf((float)degi[i], 1.0f));
    }
}

// ---------------- scan (rowptr from deg_in) ----------------
#define SCAN_B 256
__global__ void k_scan1(const int* __restrict__ deg, int* __restrict__ rowptr,
                        int* __restrict__ partials) {
    __shared__ int s[SCAN_B];
    int t = threadIdx.x;
    int i = blockIdx.x * SCAN_B + t;
    int v = (i < N_NODES) ? deg[i] : 0;
    s[t] = v;
    __syncthreads();
    for (int off = 1; off < SCAN_B; off <<= 1) {
        int add = (t >= off) ? s[t - off] : 0;
        __syncthreads();
        s[t] += add;
        __syncthreads();
    }
    if (i < N_NODES) rowptr[i + 1] = s[t];
    if (t == SCAN_B - 1) partials[blockIdx.x] = s[t];
}

#define SCAN2_T 512
__global__ void k_scan2(int* __restrict__ partials, int* __restrict__ rowptr, int nb) {
    __shared__ int s[SCAN2_T];
    int t = threadIdx.x;
    int v = (t < nb) ? partials[t] : 0;
    s[t] = v;
    __syncthreads();
    for (int off = 1; off < SCAN2_T; off <<= 1) {
        int add = (t >= off) ? s[t - off] : 0;
        __syncthreads();
        s[t] += add;
        __syncthreads();
    }
    if (t < nb) partials[t] = s[t] - v;  // exclusive
    if (t == 0) rowptr[0] = 0;
}

__global__ void k_scan3(const int* __restrict__ partials, int* __restrict__ rowptr) {
    int i = blockIdx.x * SCAN_B + threadIdx.x;
    if (i < N_NODES) rowptr[i + 1] += partials[blockIdx.x];
}

// ---------------- CSR fill ----------------
__global__ void k_fill(const int* __restrict__ src, const int* __restrict__ dst,
                       const int* __restrict__ rowptr, int* __restrict__ cursor,
                       int* __restrict__ esrc) {
    int e = blockIdx.x * blockDim.x + threadIdx.x;
    if (e < N_EDGES) {
        int d = dst[e];
        int pos = rowptr[d] + atomicAdd(&cursor[d], 1);
        esrc[pos] = src[e];
    }
}

// ---------------- embedding gather * norm_src -> bf16 ----------------
__global__ void k_embed(const int* __restrict__ tokens, const float* __restrict__ embed,
                        const float* __restrict__ ns, ushort_t* __restrict__ hs) {
    int gid = blockIdx.x * blockDim.x + threadIdx.x;  // N*16
    int node = gid >> 4;
    int sub = gid & 15;
    if (node >= N_NODES) return;
    int tok = tokens[node];
    float s = ns[node];
    const float* ep = embed + (size_t)tok * DIM + sub * 8;
    float4 a = *(const float4*)ep;
    float4 b = *(const float4*)(ep + 4);
    uint4 o;
    o.x = pack2(a.x * s, a.y * s);
    o.y = pack2(a.z * s, a.w * s);
    o.z = pack2(b.x * s, b.y * s);
    o.w = pack2(b.z * s, b.w * s);
    *(uint4*)(hs + (size_t)node * DIM + sub * 8) = o;
}

// ---------------- aggregation: one wave per node, 8-way edge unroll for MLP ----------------
__global__ void k_aggregate(const ushort_t* __restrict__ hs, const int* __restrict__ rowptr,
                            const int* __restrict__ esrc, const float* __restrict__ nd,
                            ushort_t* __restrict__ agg) {
    int wid = (blockIdx.x * blockDim.x + threadIdx.x) >> 6;
    int lane = threadIdx.x & 63;
    if (wid >= N_NODES) return;
    int beg = rowptr[wid], end = rowptr[wid + 1];
    int off = lane * 2;
    float ax0 = 0.f, ay0 = 0.f, ax1 = 0.f, ay1 = 0.f;
    float ax2 = 0.f, ay2 = 0.f, ax3 = 0.f, ay3 = 0.f;
    int e = beg;
    for (; e + 8 <= end; e += 8) {
        int s0 = esrc[e + 0], s1 = esrc[e + 1], s2 = esrc[e + 2], s3 = esrc[e + 3];
        int s4 = esrc[e + 4], s5 = esrc[e + 5], s6 = esrc[e + 6], s7 = esrc[e + 7];
        uint_t u0 = *(const uint_t*)(hs + (size_t)s0 * DIM + off);
        uint_t u1 = *(const uint_t*)(hs + (size_t)s1 * DIM + off);
        uint_t u2 = *(const uint_t*)(hs + (size_t)s2 * DIM + off);
        uint_t u3 = *(const uint_t*)(hs + (size_t)s3 * DIM + off);
        uint_t u4 = *(const uint_t*)(hs + (size_t)s4 * DIM + off);
        uint_t u5 = *(const uint_t*)(hs + (size_t)s5 * DIM + off);
        uint_t u6 = *(const uint_t*)(hs + (size_t)s6 * DIM + off);
        uint_t u7 = *(const uint_t*)(hs + (size_t)s7 * DIM + off);
        ax0 += bfl(u0); ay0 += bfh(u0);
        ax1 += bfl(u1); ay1 += bfh(u1);
        ax2 += bfl(u2); ay2 += bfh(u2);
        ax3 += bfl(u3); ay3 += bfh(u3);
        ax0 += bfl(u4); ay0 += bfh(u4);
        ax1 += bfl(u5); ay1 += bfh(u5);
        ax2 += bfl(u6); ay2 += bfh(u6);
        ax3 += bfl(u7); ay3 += bfh(u7);
    }
    for (; e < end; ++e) {
        int s = esrc[e];
        uint_t u = *(const uint_t*)(hs + (size_t)s * DIM + off);
        ax0 += bfl(u); ay0 += bfh(u);
    }
    float ax = (ax0 + ax1) + (ax2 + ax3);
    float ay = (ay0 + ay1) + (ay2 + ay3);
    float n = nd[wid];
    *(uint_t*)(agg + (size_t)wid * DIM + off) = pack2(ax * n, ay * n);
}

// ---------------- GEMM + fused BN stats:
// y[N,128](bf16) = x[N,128](bf16) @ W[128,128](f32) + bias; atomically
// accumulates column sum / sumsq of y into bnsum/bnsq. ----------------
#define GEMM_ROWS 64
__global__ __launch_bounds__(256) void k_gemm(const ushort_t* __restrict__ x,
                                              const float* __restrict__ wf,
                                              const float* __restrict__ bias,
                                              ushort_t* __restrict__ y,
                                              float* __restrict__ bnsum,
                                              float* __restrict__ bnsq) {
    __shared__ float xs[GEMM_ROWS][DIM + 4];
    __shared__ float csum[DIM];
    __shared__ float csq[DIM];
    int row0 = blockIdx.x * GEMM_ROWS;
    // stage x tile (bf16 -> f32): 64x128 = 8192 vals, 256 thr x 8 vals x 4 iters
    for (int it = 0; it < 4; ++it) {
        int slot = threadIdx.x + it * 256;  // 0..1023
        int r = slot >> 4;
        int cs = (slot & 15) * 8;
        uint4 u = make_uint4(0u, 0u, 0u, 0u);
        if (row0 + r < N_NODES)
            u = *(const uint4*)(x + (size_t)(row0 + r) * DIM + cs);
        xs[r][cs + 0] = bfl(u.x); xs[r][cs + 1] = bfh(u.x);
        xs[r][cs + 2] = bfl(u.y); xs[r][cs + 3] = bfh(u.y);
        xs[r][cs + 4] = bfl(u.z); xs[r][cs + 5] = bfh(u.z);
        xs[r][cs + 6] = bfl(u.w); xs[r][cs + 7] = bfh(u.w);
    }
    if (threadIdx.x < DIM) { csum[threadIdx.x] = 0.f; csq[threadIdx.x] = 0.f; }
    __syncthreads();

    int rowg = threadIdx.x >> 4;   // 0..15 (4 rows each)
    int colg = threadIdx.x & 15;   // 0..15 (8 cols each)
    const float* wp = wf + colg * 8;
    float acc[4][8];
#pragma unroll
    for (int j = 0; j < 4; ++j)
#pragma unroll
        for (int i = 0; i < 8; ++i) acc[j][i] = 0.f;

    for (int k0 = 0; k0 < DIM; k0 += 4) {
        float4 xv[4];
#pragma unroll
        for (int j = 0; j < 4; ++j)
            xv[j] = *(const float4*)&xs[rowg * 4 + j][k0];
#pragma unroll
        for (int kk = 0; kk < 4; ++kk) {
            float4 wa = *(const float4*)(wp + (size_t)(k0 + kk) * DIM);
            float4 wb = *(const float4*)(wp + (size_t)(k0 + kk) * DIM + 4);
#pragma unroll
            for (int j = 0; j < 4; ++j) {
                float xj = ((const float*)&xv[j])[kk];
                acc[j][0] += xj * wa.x; acc[j][1] += xj * wa.y;
                acc[j][2] += xj * wa.z; acc[j][3] += xj * wa.w;
                acc[j][4] += xj * wb.x; acc[j][5] += xj * wb.y;
                acc[j][6] += xj * wb.z; acc[j][7] += xj * wb.w;
            }
        }
    }
    // add bias, accumulate stats, write y (bf16)
    float bb[8];
#pragma unroll
    for (int i = 0; i < 8; ++i) bb[i] = bias[colg * 8 + i];
    float ps[8], pq[8];
#pragma unroll
    for (int i = 0; i < 8; ++i) { ps[i] = 0.f; pq[i] = 0.f; }
#pragma unroll
    for (int j = 0; j < 4; ++j) {
        int r = row0 + rowg * 4 + j;
        if (r < N_NODES) {
            float v[8];
#pragma unroll
            for (int i = 0; i < 8; ++i) {
                v[i] = acc[j][i] + bb[i];
                ps[i] += v[i];
                pq[i] += v[i] * v[i];
            }
            uint4 o;
            o.x = pack2(v[0], v[1]); o.y = pack2(v[2], v[3]);
            o.z = pack2(v[4], v[5]); o.w = pack2(v[6], v[7]);
            *(uint4*)(y + (size_t)r * DIM + colg * 8) = o;
        }
    }
#pragma unroll
    for (int i = 0; i < 8; ++i) {
        atomicAdd(&csum[colg * 8 + i], ps[i]);
        atomicAdd(&csq[colg * 8 + i], pq[i]);
    }
    __syncthreads();
    if (threadIdx.x < DIM) {
        atomicAdd(&bnsum[threadIdx.x], csum[threadIdx.x]);
        atomicAdd(&bnsq[threadIdx.x], csq[threadIdx.x]);
    }
}

// ---------------- BN fold ----------------
__global__ void k_bnfold(const float* __restrict__ sum, const float* __restrict__ sumsq,
                         const float* __restrict__ g, const float* __restrict__ be,
                         float* __restrict__ bna, float* __restrict__ bnc) {
    int c = threadIdx.x;  // 128
    float mu = sum[c] * (1.0f / N_NODES);
    float var = sumsq[c] * (1.0f / N_NODES) - mu * mu;
    float rstd = rsqrtf(var + BN_EPS);
    float a = g[c] * rstd;
    bna[c] = a;
    bnc[c] = be[c] - mu * a;
}

// ---------------- BN apply + relu (+ norm_src prescale), bf16 in/out ----------------
__global__ void k_bnapply(const ushort_t* __restrict__ yin, ushort_t* __restrict__ xout,
                          const float* __restrict__ bna, const float* __restrict__ bnc,
                          const float* __restrict__ scale) {
    int gid = blockIdx.x * blockDim.x + threadIdx.x;  // N*16
    int node = gid >> 4;
    int sub = gid & 15;
    if (node >= N_NODES) return;
    float s = scale ? scale[node] : 1.0f;
    uint4 u = *(const uint4*)(yin + (size_t)node * DIM + sub * 8);
    float v[8] = {bfl(u.x), bfh(u.x), bfl(u.y), bfh(u.y),
                  bfl(u.z), bfh(u.z), bfl(u.w), bfh(u.w)};
    const float* a = bna + sub * 8;
    const float* c = bnc + sub * 8;
#pragma unroll
    for (int i = 0; i < 8; ++i) v[i] = fmaxf(v[i] * a[i] + c[i], 0.f) * s;
    uint4 o;
    o.x = pack2(v[0], v[1]); o.y = pack2(v[2], v[3]);
    o.z = pack2(v[4], v[5]); o.w = pack2(v[6], v[7]);
    *(uint4*)(xout + (size_t)node * DIM + sub * 8) = o;
}

// ---------------- pooling ----------------
__global__ void k_poolcnt(const int* __restrict__ gids, int* __restrict__ cnt) {
    __shared__ int h[N_GRAPHS];
    if (threadIdx.x < N_GRAPHS) h[threadIdx.x] = 0;
    __syncthreads();
    int i = blockIdx.x * blockDim.x + threadIdx.x;
    if (i < N_NODES) atomicAdd(&h[gids[i]], 1);
    __syncthreads();
    if (threadIdx.x < N_GRAPHS) {
        int v = h[threadIdx.x];
        if (v) atomicAdd(&cnt[threadIdx.x], v);
    }
}

#define POOL_NODES 256
__global__ void k_poolsum(const ushort_t* __restrict__ h, const int* __restrict__ gids,
                          float* __restrict__ pool) {
    int col = threadIdx.x;  // 128
    int base = blockIdx.x * POOL_NODES;
    if (base >= N_NODES) return;
    int end = min(base + POOL_NODES, N_NODES);
    float acc = 0.f;
    int cur = gids[base];
    for (int n = base; n < end; ++n) {
        int g = gids[n];
        if (g != cur) {
            atomicAdd(&pool[(size_t)cur * DIM + col], acc);
            acc = 0.f;
            cur = g;
        }
        uint_t u = *(const uint_t*)(h + (size_t)n * DIM + (col & ~1));
        acc += (col & 1) ? bfh(u) : bfl(u);
    }
    atomicAdd(&pool[(size_t)cur * DIM + col], acc);
}

// ---------------- final FC (one block per graph) ----------------
__global__ void k_final(const float* __restrict__ pool, const int* __restrict__ cnt,
                        const float* __restrict__ fcW1, const float* __restrict__ fcb1,
                        const float* __restrict__ fcW2, const float* __restrict__ fcb2,
                        float* __restrict__ out) {
    __shared__ float hg[DIM];
    __shared__ float z[64];
    int g = blockIdx.x;
    int t = threadIdx.x;  // 128
    float cf = fmaxf((float)cnt[g], 1.0f);
    hg[t] = pool[(size_t)g * DIM + t] / cf;
    __syncthreads();
    if (t < 64) {
        float acc = fcb1[t];
        for (int k = 0; k < DIM; ++k)
            acc += hg[k] * fcW1[k * 64 + t];
        z[t] = fmaxf(acc, 0.f);
    }
    __syncthreads();
    if (t < 2) {
        float acc = fcb2[t];
        for (int k = 0; k < 64; ++k)
            acc += z[k] * fcW2[k * 2 + t];
        out[g * 2 + t] = acc;
    }
}

extern "C" void kernel_launch(void* const* d_in, const int* in_sizes, int n_in,
                              void* d_out, int out_size, void* d_ws, size_t ws_size,
                              hipStream_t stream) {
    const int* tokens = (const int*)d_in[0];
    const int* src = (const int*)d_in[1];
    const int* dst = (const int*)d_in[2];
    const int* gids = (const int*)d_in[3];
    const float* embed = (const float*)d_in[4];
    const float* W1 = (const float*)d_in[5];
    const float* b1 = (const float*)d_in[6];
    const float* g1 = (const float*)d_in[7];
    const float* be1 = (const float*)d_in[8];
    const float* W2 = (const float*)d_in[9];
    const float* b2 = (const float*)d_in[10];
    const float* g2 = (const float*)d_in[11];
    const float* be2 = (const float*)d_in[12];
    const float* W3 = (const float*)d_in[13];
    const float* b3 = (const float*)d_in[14];
    const float* g3 = (const float*)d_in[15];
    const float* be3 = (const float*)d_in[16];
    const float* fcW1 = (const float*)d_in[17];
    const float* fcb1 = (const float*)d_in[18];
    const float* fcW2 = (const float*)d_in[19];
    const float* fcb2 = (const float*)d_in[20];
    float* out = (float*)d_out;

    char* w = (char*)d_ws;
    auto alloc = [&](size_t bytes) {
        void* p = (void*)w;
        w += (bytes + 255) & ~(size_t)255;
        return p;
    };
    // bf16 feature buffers (25.6 MB each)
    ushort_t* bufX = (ushort_t*)alloc((size_t)N_NODES * DIM * 2);   // aggregate input
    ushort_t* bufAgg = (ushort_t*)alloc((size_t)N_NODES * DIM * 2); // aggregate out / gemm x
    ushort_t* bufY = (ushort_t*)alloc((size_t)N_NODES * DIM * 2);   // gemm out (pre-BN)
    int* esrc = (int*)alloc((size_t)N_EDGES * 4);
    int* rowptr = (int*)alloc((size_t)(N_NODES + 1) * 4);
    float* ns = (float*)alloc((size_t)N_NODES * 4);
    float* nd = (float*)alloc((size_t)N_NODES * 4);
    float* bna = (float*)alloc(3 * DIM * 4);
    float* bnc = (float*)alloc(3 * DIM * 4);
    int* partials = (int*)alloc(1024 * 4);
    // zeroed region (contiguous)
    char* zstart = w;
    int* dego = (int*)alloc((size_t)N_NODES * 4);
    int* degi = (int*)alloc((size_t)N_NODES * 4);
    int* cursor = (int*)alloc((size_t)N_NODES * 4);
    float* bnsum = (float*)alloc(3 * DIM * 4);
    float* bnsq = (float*)alloc(3 * DIM * 4);
    float* pool = (float*)alloc((size_t)N_GRAPHS * DIM * 4);
    int* cnt = (int*)alloc((size_t)N_GRAPHS * 4);
    int zwords = (int)((size_t)(w - zstart) / 4);

    int nb_e = (N_EDGES + 255) / 256;
    int nb_n = (N_NODES + 255) / 256;
    int nb_scan = (N_NODES + SCAN_B - 1) / SCAN_B;

    k_zero<<<(zwords + 255) / 256, 256, 0, stream>>>((int*)zstart, zwords);
    k_degrees<<<nb_e, 256, 0, stream>>>(src, dst, dego, degi);
    k_norms<<<nb_n, 256, 0, stream>>>(dego, degi, ns, nd);
    k_scan1<<<nb_scan, SCAN_B, 0, stream>>>(degi, rowptr, partials);
    k_scan2<<<1, SCAN2_T, 0, stream>>>(partials, rowptr, nb_scan);
    k_scan3<<<nb_scan, SCAN_B, 0, stream>>>(partials, rowptr);
    k_fill<<<nb_e, 256, 0, stream>>>(src, dst, rowptr, cursor, esrc);
    k_embed<<<(N_NODES * 16 + 255) / 256, 256, 0, stream>>>(tokens, embed, ns, bufX);

    const float* W_l[3] = {W1, W2, W3};
    const float* bias_l[3] = {b1, b2, b3};
    const float* g_l[3] = {g1, g2, g3};
    const float* be_l[3] = {be1, be2, be3};
    int nb_agg = (N_NODES * 64 + 255) / 256;
    int nb_gemm = (N_NODES + GEMM_ROWS - 1) / GEMM_ROWS;
    int nb_el = (N_NODES * 16 + 255) / 256;

    for (int l = 0; l < 3; ++l) {
        k_aggregate<<<nb_agg, 256, 0, stream>>>(bufX, rowptr, esrc, nd, bufAgg);
        k_gemm<<<nb_gemm, 256, 0, stream>>>(bufAgg, W_l[l], bias_l[l], bufY,
                                            bnsum + l * DIM, bnsq + l * DIM);
        k_bnfold<<<1, DIM, 0, stream>>>(bnsum + l * DIM, bnsq + l * DIM, g_l[l], be_l[l],
                                        bna + l * DIM, bnc + l * DIM);
        k_bnapply<<<nb_el, 256, 0, stream>>>(bufY, bufX, bna + l * DIM, bnc + l * DIM,
                                             (l < 2) ? ns : (const float*)nullptr);
    }

    k_poolcnt<<<nb_n, 256, 0, stream>>>(gids, cnt);
    k_poolsum<<<(N_NODES + POOL_NODES - 1) / POOL_NODES, DIM, 0, stream>>>(bufX, gids, pool);
    k_final<<<N_GRAPHS, DIM, 0, stream>>>(pool, cnt, fcW1, fcb1, fcW2, fcb2, out);
}

// Round 7
// 858.001 us; speedup vs baseline: 2.2976x; 1.1683x over previous
//
#include <hip/hip_runtime.h>

#define N_NODES 100000
#define N_EDGES 1600000
#define N_GRAPHS 64
#define DIM 128
#define BN_EPS 1e-5f

typedef unsigned short ushort_t;
typedef unsigned int uint_t;
typedef __attribute__((ext_vector_type(8))) short bf16x8;
typedef __attribute__((ext_vector_type(4))) float f32x4;

__device__ __forceinline__ float bfl(uint_t u) {
    union { uint_t i; float f; } v; v.i = u << 16; return v.f;
}
__device__ __forceinline__ float bfh(uint_t u) {
    union { uint_t i; float f; } v; v.i = u & 0xffff0000u; return v.f;
}
__device__ __forceinline__ ushort_t f2bf(float f) {
    union { float f; uint_t i; } v; v.f = f;
    uint_t x = v.i;
    return (ushort_t)((x + 0x7fffu + ((x >> 16) & 1u)) >> 16);
}
__device__ __forceinline__ uint_t pack2(float lo, float hi) {
    return ((uint_t)f2bf(hi) << 16) | (uint_t)f2bf(lo);
}

// ---------------- zero scratch ----------------
__global__ void k_zero(int* __restrict__ p, int n) {
    int i = blockIdx.x * blockDim.x + threadIdx.x;
    if (i < n) p[i] = 0;
}

// ---------------- degrees + per-edge position (atomic return value) ----------------
__global__ void k_degpos(const int* __restrict__ src, const int* __restrict__ dst,
                         int* __restrict__ dego, int* __restrict__ degi,
                         ushort_t* __restrict__ pos) {
    int e = blockIdx.x * blockDim.x + threadIdx.x;
    if (e < N_EDGES) {
        atomicAdd(&dego[src[e]], 1);
        int p = atomicAdd(&degi[dst[e]], 1);
        pos[e] = (ushort_t)p;
    }
}

__global__ void k_norms(const int* __restrict__ dego, const int* __restrict__ degi,
                        float* __restrict__ ns, float* __restrict__ nd) {
    int i = blockIdx.x * blockDim.x + threadIdx.x;
    if (i < N_NODES) {
        ns[i] = rsqrtf(fmaxf((float)dego[i], 1.0f));
        nd[i] = rsqrtf(fmaxf((float)degi[i], 1.0f));
    }
}

// ---------------- scan (rowptr from deg_in) ----------------
#define SCAN_B 256
__global__ void k_scan1(const int* __restrict__ deg, int* __restrict__ rowptr,
                        int* __restrict__ partials) {
    __shared__ int s[SCAN_B];
    int t = threadIdx.x;
    int i = blockIdx.x * SCAN_B + t;
    int v = (i < N_NODES) ? deg[i] : 0;
    s[t] = v;
    __syncthreads();
    for (int off = 1; off < SCAN_B; off <<= 1) {
        int add = (t >= off) ? s[t - off] : 0;
        __syncthreads();
        s[t] += add;
        __syncthreads();
    }
    if (i < N_NODES) rowptr[i + 1] = s[t];
    if (t == SCAN_B - 1) partials[blockIdx.x] = s[t];
}

#define SCAN2_T 512
__global__ void k_scan2(int* __restrict__ partials, int* __restrict__ rowptr, int nb) {
    __shared__ int s[SCAN2_T];
    int t = threadIdx.x;
    int v = (t < nb) ? partials[t] : 0;
    s[t] = v;
    __syncthreads();
    for (int off = 1; off < SCAN2_T; off <<= 1) {
        int add = (t >= off) ? s[t - off] : 0;
        __syncthreads();
        s[t] += add;
        __syncthreads();
    }
    if (t < nb) partials[t] = s[t] - v;  // exclusive
    if (t == 0) rowptr[0] = 0;
}

__global__ void k_scan3(const int* __restrict__ partials, int* __restrict__ rowptr) {
    int i = blockIdx.x * SCAN_B + threadIdx.x;
    if (i < N_NODES) rowptr[i + 1] += partials[blockIdx.x];
}

// ---------------- CSR scatter (atomic-free) ----------------
__global__ void k_scatter(const int* __restrict__ src, const int* __restrict__ dst,
                          const int* __restrict__ rowptr, const ushort_t* __restrict__ pos,
                          int* __restrict__ esrc) {
    int e = blockIdx.x * blockDim.x + threadIdx.x;
    if (e < N_EDGES) {
        int d = dst[e];
        esrc[rowptr[d] + (int)pos[e]] = src[e];
    }
}

// ---------------- W fp32 [k][n] -> bf16 transposed [n][k] ----------------
__global__ void k_wprep(const float* __restrict__ w1, const float* __restrict__ w2,
                        const float* __restrict__ w3, ushort_t* __restrict__ wbt) {
    int i = blockIdx.x * blockDim.x + threadIdx.x;
    if (i < 3 * DIM * DIM) {
        int l = i >> 14;
        int idx = i & (DIM * DIM - 1);
        int n = idx >> 7;
        int k = idx & (DIM - 1);
        const float* w = (l == 0) ? w1 : (l == 1) ? w2 : w3;
        wbt[i] = f2bf(w[k * DIM + n]);
    }
}

// ---------------- embedding gather * norm_src -> bf16 ----------------
__global__ void k_embed(const int* __restrict__ tokens, const float* __restrict__ embed,
                        const float* __restrict__ ns, ushort_t* __restrict__ hs) {
    int gid = blockIdx.x * blockDim.x + threadIdx.x;  // N*16
    int node = gid >> 4;
    int sub = gid & 15;
    if (node >= N_NODES) return;
    int tok = tokens[node];
    float s = ns[node];
    const float* ep = embed + (size_t)tok * DIM + sub * 8;
    float4 a = *(const float4*)ep;
    float4 b = *(const float4*)(ep + 4);
    uint4 o;
    o.x = pack2(a.x * s, a.y * s);
    o.y = pack2(a.z * s, a.w * s);
    o.z = pack2(b.x * s, b.y * s);
    o.w = pack2(b.z * s, b.w * s);
    *(uint4*)(hs + (size_t)node * DIM + sub * 8) = o;
}

// ---------------- aggregation: one wave per node, 8-way edge unroll ----------------
__global__ void k_aggregate(const ushort_t* __restrict__ hs, const int* __restrict__ rowptr,
                            const int* __restrict__ esrc, const float* __restrict__ nd,
                            ushort_t* __restrict__ agg) {
    int wid = (blockIdx.x * blockDim.x + threadIdx.x) >> 6;
    int lane = threadIdx.x & 63;
    if (wid >= N_NODES) return;
    int beg = rowptr[wid], end = rowptr[wid + 1];
    int off = lane * 2;
    float ax0 = 0.f, ay0 = 0.f, ax1 = 0.f, ay1 = 0.f;
    float ax2 = 0.f, ay2 = 0.f, ax3 = 0.f, ay3 = 0.f;
    int e = beg;
    for (; e + 8 <= end; e += 8) {
        int s0 = esrc[e + 0], s1 = esrc[e + 1], s2 = esrc[e + 2], s3 = esrc[e + 3];
        int s4 = esrc[e + 4], s5 = esrc[e + 5], s6 = esrc[e + 6], s7 = esrc[e + 7];
        uint_t u0 = *(const uint_t*)(hs + (size_t)s0 * DIM + off);
        uint_t u1 = *(const uint_t*)(hs + (size_t)s1 * DIM + off);
        uint_t u2 = *(const uint_t*)(hs + (size_t)s2 * DIM + off);
        uint_t u3 = *(const uint_t*)(hs + (size_t)s3 * DIM + off);
        uint_t u4 = *(const uint_t*)(hs + (size_t)s4 * DIM + off);
        uint_t u5 = *(const uint_t*)(hs + (size_t)s5 * DIM + off);
        uint_t u6 = *(const uint_t*)(hs + (size_t)s6 * DIM + off);
        uint_t u7 = *(const uint_t*)(hs + (size_t)s7 * DIM + off);
        ax0 += bfl(u0); ay0 += bfh(u0);
        ax1 += bfl(u1); ay1 += bfh(u1);
        ax2 += bfl(u2); ay2 += bfh(u2);
        ax3 += bfl(u3); ay3 += bfh(u3);
        ax0 += bfl(u4); ay0 += bfh(u4);
        ax1 += bfl(u5); ay1 += bfh(u5);
        ax2 += bfl(u6); ay2 += bfh(u6);
        ax3 += bfl(u7); ay3 += bfh(u7);
    }
    for (; e < end; ++e) {
        int s = esrc[e];
        uint_t u = *(const uint_t*)(hs + (size_t)s * DIM + off);
        ax0 += bfl(u); ay0 += bfh(u);
    }
    float ax = (ax0 + ax1) + (ax2 + ax3);
    float ay = (ay0 + ay1) + (ay2 + ay3);
    float n = nd[wid];
    *(uint_t*)(agg + (size_t)wid * DIM + off) = pack2(ax * n, ay * n);
}

// ---------------- MFMA GEMM + fused BN stats:
// y[N,128](bf16) = x[N,128](bf16) @ W[128,128] + bias, W given bf16-transposed [n][k].
// Layouts (HW-verified gfx950 16x16x32 bf16): A[m=lane&15][k=quad*8+j],
// B[k=quad*8+j][n=lane&15], D col=lane&15, row=quad*4+reg. ----------------
__global__ __launch_bounds__(256) void k_gemm(const ushort_t* __restrict__ x,
                                              const ushort_t* __restrict__ wbt,
                                              const float* __restrict__ bias,
                                              ushort_t* __restrict__ y,
                                              float* __restrict__ bnsum,
                                              float* __restrict__ bnsq) {
    __shared__ float csum[DIM];
    __shared__ float csq[DIM];
    if (threadIdx.x < DIM) { csum[threadIdx.x] = 0.f; csq[threadIdx.x] = 0.f; }
    __syncthreads();

    int wave = threadIdx.x >> 6;   // 0..3
    int lane = threadIdx.x & 63;
    int m16 = lane & 15;
    int quad = lane >> 4;          // 0..3
    int row0 = blockIdx.x * 64 + wave * 16;

    f32x4 acc[8];
#pragma unroll
    for (int nb = 0; nb < 8; ++nb) acc[nb] = (f32x4)(0.f);

    int arow = row0 + m16;
    bool rowok = arow < N_NODES;
    const ushort_t* xp = x + (size_t)arow * DIM + quad * 8;

#pragma unroll
    for (int k0 = 0; k0 < DIM; k0 += 32) {
        bf16x8 af;
        if (rowok) af = *(const bf16x8*)(xp + k0);
        else af = (bf16x8)(short)0;
#pragma unroll
        for (int nb = 0; nb < 8; ++nb) {
            int ncol = nb * 16 + m16;
            bf16x8 bfg = *(const bf16x8*)(wbt + (size_t)ncol * DIM + k0 + quad * 8);
            acc[nb] = __builtin_amdgcn_mfma_f32_16x16x32_bf16(af, bfg, acc[nb], 0, 0, 0);
        }
    }

    // epilogue: bias, BN partial stats, bf16 store
#pragma unroll
    for (int nb = 0; nb < 8; ++nb) {
        int col = nb * 16 + m16;
        float bcol = bias[col];
        float ps = 0.f, pq = 0.f;
#pragma unroll
        for (int reg = 0; reg < 4; ++reg) {
            int r = row0 + quad * 4 + reg;
            if (r < N_NODES) {
                float v = acc[nb][reg] + bcol;
                ps += v; pq += v * v;
                y[(size_t)r * DIM + col] = f2bf(v);
            }
        }
        atomicAdd(&csum[col], ps);
        atomicAdd(&csq[col], pq);
    }
    __syncthreads();
    if (threadIdx.x < DIM) {
        atomicAdd(&bnsum[threadIdx.x], csum[threadIdx.x]);
        atomicAdd(&bnsq[threadIdx.x], csq[threadIdx.x]);
    }
}

// ---------------- BN fold ----------------
__global__ void k_bnfold(const float* __restrict__ sum, const float* __restrict__ sumsq,
                         const float* __restrict__ g, const float* __restrict__ be,
                         float* __restrict__ bna, float* __restrict__ bnc) {
    int c = threadIdx.x;  // 128
    float mu = sum[c] * (1.0f / N_NODES);
    float var = sumsq[c] * (1.0f / N_NODES) - mu * mu;
    float rstd = rsqrtf(var + BN_EPS);
    float a = g[c] * rstd;
    bna[c] = a;
    bnc[c] = be[c] - mu * a;
}

// ---------------- BN apply + relu (+ norm_src prescale), bf16 in/out ----------------
__global__ void k_bnapply(const ushort_t* __restrict__ yin, ushort_t* __restrict__ xout,
                          const float* __restrict__ bna, const float* __restrict__ bnc,
                          const float* __restrict__ scale) {
    int gid = blockIdx.x * blockDim.x + threadIdx.x;  // N*16
    int node = gid >> 4;
    int sub = gid & 15;
    if (node >= N_NODES) return;
    float s = scale ? scale[node] : 1.0f;
    uint4 u = *(const uint4*)(yin + (size_t)node * DIM + sub * 8);
    float v[8] = {bfl(u.x), bfh(u.x), bfl(u.y), bfh(u.y),
                  bfl(u.z), bfh(u.z), bfl(u.w), bfh(u.w)};
    const float* a = bna + sub * 8;
    const float* c = bnc + sub * 8;
#pragma unroll
    for (int i = 0; i < 8; ++i) v[i] = fmaxf(v[i] * a[i] + c[i], 0.f) * s;
    uint4 o;
    o.x = pack2(v[0], v[1]); o.y = pack2(v[2], v[3]);
    o.z = pack2(v[4], v[5]); o.w = pack2(v[6], v[7]);
    *(uint4*)(xout + (size_t)node * DIM + sub * 8) = o;
}

// ---------------- pooling ----------------
__global__ void k_poolcnt(const int* __restrict__ gids, int* __restrict__ cnt) {
    __shared__ int h[N_GRAPHS];
    if (threadIdx.x < N_GRAPHS) h[threadIdx.x] = 0;
    __syncthreads();
    int i = blockIdx.x * blockDim.x + threadIdx.x;
    if (i < N_NODES) atomicAdd(&h[gids[i]], 1);
    __syncthreads();
    if (threadIdx.x < N_GRAPHS) {
        int v = h[threadIdx.x];
        if (v) atomicAdd(&cnt[threadIdx.x], v);
    }
}

#define POOL_NODES 256
__global__ void k_poolsum(const ushort_t* __restrict__ h, const int* __restrict__ gids,
                          float* __restrict__ pool) {
    int col = threadIdx.x;  // 128
    int base = blockIdx.x * POOL_NODES;
    if (base >= N_NODES) return;
    int end = min(base + POOL_NODES, N_NODES);
    float acc = 0.f;
    int cur = gids[base];
    for (int n = base; n < end; ++n) {
        int g = gids[n];
        if (g != cur) {
            atomicAdd(&pool[(size_t)cur * DIM + col], acc);
            acc = 0.f;
            cur = g;
        }
        uint_t u = *(const uint_t*)(h + (size_t)n * DIM + (col & ~1));
        acc += (col & 1) ? bfh(u) : bfl(u);
    }
    atomicAdd(&pool[(size_t)cur * DIM + col], acc);
}

// ---------------- final FC (one block per graph) ----------------
__global__ void k_final(const float* __restrict__ pool, const int* __restrict__ cnt,
                        const float* __restrict__ fcW1, const float* __restrict__ fcb1,
                        const float* __restrict__ fcW2, const float* __restrict__ fcb2,
                        float* __restrict__ out) {
    __shared__ float hg[DIM];
    __shared__ float z[64];
    int g = blockIdx.x;
    int t = threadIdx.x;  // 128
    float cf = fmaxf((float)cnt[g], 1.0f);
    hg[t] = pool[(size_t)g * DIM + t] / cf;
    __syncthreads();
    if (t < 64) {
        float acc = fcb1[t];
        for (int k = 0; k < DIM; ++k)
            acc += hg[k] * fcW1[k * 64 + t];
        z[t] = fmaxf(acc, 0.f);
    }
    __syncthreads();
    if (t < 2) {
        float acc = fcb2[t];
        for (int k = 0; k < 64; ++k)
            acc += z[k] * fcW2[k * 2 + t];
        out[g * 2 + t] = acc;
    }
}

extern "C" void kernel_launch(void* const* d_in, const int* in_sizes, int n_in,
                              void* d_out, int out_size, void* d_ws, size_t ws_size,
                              hipStream_t stream) {
    const int* tokens = (const int*)d_in[0];
    const int* src = (const int*)d_in[1];
    const int* dst = (const int*)d_in[2];
    const int* gids = (const int*)d_in[3];
    const float* embed = (const float*)d_in[4];
    const float* W1 = (const float*)d_in[5];
    const float* b1 = (const float*)d_in[6];
    const float* g1 = (const float*)d_in[7];
    const float* be1 = (const float*)d_in[8];
    const float* W2 = (const float*)d_in[9];
    const float* b2 = (const float*)d_in[10];
    const float* g2 = (const float*)d_in[11];
    const float* be2 = (const float*)d_in[12];
    const float* W3 = (const float*)d_in[13];
    const float* b3 = (const float*)d_in[14];
    const float* g3 = (const float*)d_in[15];
    const float* be3 = (const float*)d_in[16];
    const float* fcW1 = (const float*)d_in[17];
    const float* fcb1 = (const float*)d_in[18];
    const float* fcW2 = (const float*)d_in[19];
    const float* fcb2 = (const float*)d_in[20];
    float* out = (float*)d_out;

    char* w = (char*)d_ws;
    auto alloc = [&](size_t bytes) {
        void* p = (void*)w;
        w += (bytes + 255) & ~(size_t)255;
        return p;
    };
    // bf16 feature buffers (25.6 MB each)
    ushort_t* bufX = (ushort_t*)alloc((size_t)N_NODES * DIM * 2);   // aggregate input
    ushort_t* bufAgg = (ushort_t*)alloc((size_t)N_NODES * DIM * 2); // aggregate out / gemm x
    ushort_t* bufY = (ushort_t*)alloc((size_t)N_NODES * DIM * 2);   // gemm out (pre-BN)
    int* esrc = (int*)alloc((size_t)N_EDGES * 4);
    ushort_t* pos = (ushort_t*)alloc((size_t)N_EDGES * 2);
    int* rowptr = (int*)alloc((size_t)(N_NODES + 1) * 4);
    float* ns = (float*)alloc((size_t)N_NODES * 4);
    float* nd = (float*)alloc((size_t)N_NODES * 4);
    float* bna = (float*)alloc(3 * DIM * 4);
    float* bnc = (float*)alloc(3 * DIM * 4);
    int* partials = (int*)alloc(1024 * 4);
    ushort_t* wbt = (ushort_t*)alloc(3 * DIM * DIM * 2);
    // zeroed region (contiguous)
    char* zstart = w;
    int* dego = (int*)alloc((size_t)N_NODES * 4);
    int* degi = (int*)alloc((size_t)N_NODES * 4);
    float* bnsum = (float*)alloc(3 * DIM * 4);
    float* bnsq = (float*)alloc(3 * DIM * 4);
    float* pool = (float*)alloc((size_t)N_GRAPHS * DIM * 4);
    int* cnt = (int*)alloc((size_t)N_GRAPHS * 4);
    int zwords = (int)((size_t)(w - zstart) / 4);

    int nb_e = (N_EDGES + 255) / 256;
    int nb_n = (N_NODES + 255) / 256;
    int nb_scan = (N_NODES + SCAN_B - 1) / SCAN_B;

    k_zero<<<(zwords + 255) / 256, 256, 0, stream>>>((int*)zstart, zwords);
    k_degpos<<<nb_e, 256, 0, stream>>>(src, dst, dego, degi, pos);
    k_norms<<<nb_n, 256, 0, stream>>>(dego, degi, ns, nd);
    k_scan1<<<nb_scan, SCAN_B, 0, stream>>>(degi, rowptr, partials);
    k_scan2<<<1, SCAN2_T, 0, stream>>>(partials, rowptr, nb_scan);
    k_scan3<<<nb_scan, SCAN_B, 0, stream>>>(partials, rowptr);
    k_scatter<<<nb_e, 256, 0, stream>>>(src, dst, rowptr, pos, esrc);
    k_wprep<<<(3 * DIM * DIM + 255) / 256, 256, 0, stream>>>(W1, W2, W3, wbt);
    k_embed<<<(N_NODES * 16 + 255) / 256, 256, 0, stream>>>(tokens, embed, ns, bufX);

    const float* bias_l[3] = {b1, b2, b3};
    const float* g_l[3] = {g1, g2, g3};
    const float* be_l[3] = {be1, be2, be3};
    int nb_agg = (N_NODES * 64 + 255) / 256;
    int nb_gemm = (N_NODES + 63) / 64;
    int nb_el = (N_NODES * 16 + 255) / 256;

    for (int l = 0; l < 3; ++l) {
        k_aggregate<<<nb_agg, 256, 0, stream>>>(bufX, rowptr, esrc, nd, bufAgg);
        k_gemm<<<nb_gemm, 256, 0, stream>>>(bufAgg, wbt + (size_t)l * DIM * DIM, bias_l[l],
                                            bufY, bnsum + l * DIM, bnsq + l * DIM);
        k_bnfold<<<1, DIM, 0, stream>>>(bnsum + l * DIM, bnsq + l * DIM, g_l[l], be_l[l],
                                        bna + l * DIM, bnc + l * DIM);
        k_bnapply<<<nb_el, 256, 0, stream>>>(bufY, bufX, bna + l * DIM, bnc + l * DIM,
                                             (l < 2) ? ns : (const float*)nullptr);
    }

    k_poolcnt<<<nb_n, 256, 0, stream>>>(gids, cnt);
    k_poolsum<<<(N_NODES + POOL_NODES - 1) / POOL_NODES, DIM, 0, stream>>>(bufX, gids, pool);
    k_final<<<N_GRAPHS, DIM, 0, stream>>>(pool, cnt, fcW1, fcb1, fcW2, fcb2, out);
}

// Round 8
// 775.917 us; speedup vs baseline: 2.5406x; 1.1058x over previous
//
#include <hip/hip_runtime.h>

#define N_NODES 100000
#define N_EDGES 1600000
#define N_GRAPHS 64
#define DIM 128
#define BN_EPS 1e-5f
#define EPAD (N_EDGES + 4 * N_NODES)

typedef unsigned short ushort_t;
typedef unsigned int uint_t;
typedef __attribute__((ext_vector_type(8))) short bf16x8;
typedef __attribute__((ext_vector_type(4))) float f32x4;

__device__ __forceinline__ float bfl(uint_t u) {
    union { uint_t i; float f; } v; v.i = u << 16; return v.f;
}
__device__ __forceinline__ float bfh(uint_t u) {
    union { uint_t i; float f; } v; v.i = u & 0xffff0000u; return v.f;
}
__device__ __forceinline__ ushort_t f2bf(float f) {
    union { float f; uint_t i; } v; v.f = f;
    uint_t x = v.i;
    return (ushort_t)((x + 0x7fffu + ((x >> 16) & 1u)) >> 16);
}
__device__ __forceinline__ uint_t pack2(float lo, float hi) {
    return ((uint_t)f2bf(hi) << 16) | (uint_t)f2bf(lo);
}

// ---------------- zero scratch ----------------
__global__ void k_zero(int* __restrict__ p, int n) {
    int i = blockIdx.x * blockDim.x + threadIdx.x;
    if (i < n) p[i] = 0;
}

// ---------------- esrc sentinel init + zero sentinel feature row ----------------
__global__ void k_sent(int* __restrict__ esrc, ushort_t* __restrict__ hs) {
    int i = blockIdx.x * blockDim.x + threadIdx.x;
    if (i < EPAD) esrc[i] = N_NODES;
    if (i < DIM / 2) ((uint_t*)(hs + (size_t)N_NODES * DIM))[i] = 0u;
}

// ---------------- degrees + per-edge position (atomic return value) ----------------
__global__ void k_degpos(const int* __restrict__ src, const int* __restrict__ dst,
                         int* __restrict__ dego, int* __restrict__ degi,
                         ushort_t* __restrict__ pos) {
    int e = blockIdx.x * blockDim.x + threadIdx.x;
    if (e < N_EDGES) {
        atomicAdd(&dego[src[e]], 1);
        int p = atomicAdd(&degi[dst[e]], 1);
        pos[e] = (ushort_t)p;
    }
}

__global__ void k_norms(const int* __restrict__ dego, const int* __restrict__ degi,
                        float* __restrict__ ns, float* __restrict__ nd) {
    int i = blockIdx.x * blockDim.x + threadIdx.x;
    if (i < N_NODES) {
        ns[i] = rsqrtf(fmaxf((float)dego[i], 1.0f));
        nd[i] = rsqrtf(fmaxf((float)degi[i], 1.0f));
    }
}

// ---------------- scan (rowptr from deg_in, padded to multiple of 4) ----------------
#define SCAN_B 256
__global__ void k_scan1(const int* __restrict__ deg, int* __restrict__ rowptr,
                        int* __restrict__ partials) {
    __shared__ int s[SCAN_B];
    int t = threadIdx.x;
    int i = blockIdx.x * SCAN_B + t;
    int v = (i < N_NODES) ? ((deg[i] + 3) & ~3) : 0;
    s[t] = v;
    __syncthreads();
    for (int off = 1; off < SCAN_B; off <<= 1) {
        int add = (t >= off) ? s[t - off] : 0;
        __syncthreads();
        s[t] += add;
        __syncthreads();
    }
    if (i < N_NODES) rowptr[i + 1] = s[t];
    if (t == SCAN_B - 1) partials[blockIdx.x] = s[t];
}

#define SCAN2_T 512
__global__ void k_scan2(int* __restrict__ partials, int* __restrict__ rowptr, int nb) {
    __shared__ int s[SCAN2_T];
    int t = threadIdx.x;
    int v = (t < nb) ? partials[t] : 0;
    s[t] = v;
    __syncthreads();
    for (int off = 1; off < SCAN2_T; off <<= 1) {
        int add = (t >= off) ? s[t - off] : 0;
        __syncthreads();
        s[t] += add;
        __syncthreads();
    }
    if (t < nb) partials[t] = s[t] - v;  // exclusive
    if (t == 0) rowptr[0] = 0;
}

__global__ void k_scan3(const int* __restrict__ partials, int* __restrict__ rowptr) {
    int i = blockIdx.x * SCAN_B + threadIdx.x;
    if (i < N_NODES) rowptr[i + 1] += partials[blockIdx.x];
}

// ---------------- CSR scatter (atomic-free) ----------------
__global__ void k_scatter(const int* __restrict__ src, const int* __restrict__ dst,
                          const int* __restrict__ rowptr, const ushort_t* __restrict__ pos,
                          int* __restrict__ esrc) {
    int e = blockIdx.x * blockDim.x + threadIdx.x;
    if (e < N_EDGES) {
        int d = dst[e];
        esrc[rowptr[d] + (int)pos[e]] = src[e];
    }
}

// ---------------- W fp32 [k][n] -> bf16 transposed [n][k] ----------------
__global__ void k_wprep(const float* __restrict__ w1, const float* __restrict__ w2,
                        const float* __restrict__ w3, ushort_t* __restrict__ wbt) {
    int i = blockIdx.x * blockDim.x + threadIdx.x;
    if (i < 3 * DIM * DIM) {
        int l = i >> 14;
        int idx = i & (DIM * DIM - 1);
        int n = idx >> 7;
        int k = idx & (DIM - 1);
        const float* w = (l == 0) ? w1 : (l == 1) ? w2 : w3;
        wbt[i] = f2bf(w[k * DIM + n]);
    }
}

// ---------------- embedding gather * norm_src -> bf16 ----------------
__global__ void k_embed(const int* __restrict__ tokens, const float* __restrict__ embed,
                        const float* __restrict__ ns, ushort_t* __restrict__ hs) {
    int gid = blockIdx.x * blockDim.x + threadIdx.x;  // N*16
    int node = gid >> 4;
    int sub = gid & 15;
    if (node >= N_NODES) return;
    int tok = tokens[node];
    float s = ns[node];
    const float* ep = embed + (size_t)tok * DIM + sub * 8;
    float4 a = *(const float4*)ep;
    float4 b = *(const float4*)(ep + 4);
    uint4 o;
    o.x = pack2(a.x * s, a.y * s);
    o.y = pack2(a.z * s, a.w * s);
    o.z = pack2(b.x * s, b.y * s);
    o.w = pack2(b.z * s, b.w * s);
    *(uint4*)(hs + (size_t)node * DIM + sub * 8) = o;
}

// ---------------- aggregation: one wave per node, int4 index broadcast,
// rows padded to x4 with sentinel row N_NODES (zeros) ----------------
__global__ void k_aggregate(const ushort_t* __restrict__ hs, const int* __restrict__ rowptr,
                            const int* __restrict__ esrc, const float* __restrict__ nd,
                            ushort_t* __restrict__ agg) {
    int wid = (blockIdx.x * blockDim.x + threadIdx.x) >> 6;
    int lane = threadIdx.x & 63;
    if (wid >= N_NODES) return;
    int beg = rowptr[wid], end = rowptr[wid + 1];  // count is multiple of 4, beg 4-aligned
    int off = lane * 2;
    float ax0 = 0.f, ay0 = 0.f, ax1 = 0.f, ay1 = 0.f;
    float ax2 = 0.f, ay2 = 0.f, ax3 = 0.f, ay3 = 0.f;
    int e = beg;
    for (; e + 8 <= end; e += 8) {
        int4 i0 = *(const int4*)(esrc + e);
        int4 i1 = *(const int4*)(esrc + e + 4);
        uint_t u0 = *(const uint_t*)(hs + (size_t)i0.x * DIM + off);
        uint_t u1 = *(const uint_t*)(hs + (size_t)i0.y * DIM + off);
        uint_t u2 = *(const uint_t*)(hs + (size_t)i0.z * DIM + off);
        uint_t u3 = *(const uint_t*)(hs + (size_t)i0.w * DIM + off);
        uint_t u4 = *(const uint_t*)(hs + (size_t)i1.x * DIM + off);
        uint_t u5 = *(const uint_t*)(hs + (size_t)i1.y * DIM + off);
        uint_t u6 = *(const uint_t*)(hs + (size_t)i1.z * DIM + off);
        uint_t u7 = *(const uint_t*)(hs + (size_t)i1.w * DIM + off);
        ax0 += bfl(u0); ay0 += bfh(u0);
        ax1 += bfl(u1); ay1 += bfh(u1);
        ax2 += bfl(u2); ay2 += bfh(u2);
        ax3 += bfl(u3); ay3 += bfh(u3);
        ax0 += bfl(u4); ay0 += bfh(u4);
        ax1 += bfl(u5); ay1 += bfh(u5);
        ax2 += bfl(u6); ay2 += bfh(u6);
        ax3 += bfl(u7); ay3 += bfh(u7);
    }
    if (e < end) {  // remaining 4
        int4 i0 = *(const int4*)(esrc + e);
        uint_t u0 = *(const uint_t*)(hs + (size_t)i0.x * DIM + off);
        uint_t u1 = *(const uint_t*)(hs + (size_t)i0.y * DIM + off);
        uint_t u2 = *(const uint_t*)(hs + (size_t)i0.z * DIM + off);
        uint_t u3 = *(const uint_t*)(hs + (size_t)i0.w * DIM + off);
        ax0 += bfl(u0); ay0 += bfh(u0);
        ax1 += bfl(u1); ay1 += bfh(u1);
        ax2 += bfl(u2); ay2 += bfh(u2);
        ax3 += bfl(u3); ay3 += bfh(u3);
    }
    float ax = (ax0 + ax1) + (ax2 + ax3);
    float ay = (ay0 + ay1) + (ay2 + ay3);
    float n = nd[wid];
    *(uint_t*)(agg + (size_t)wid * DIM + off) = pack2(ax * n, ay * n);
}

// ---------------- MFMA GEMM + fused BN stats, B staged in LDS fragment-order.
// Layouts (HW-verified gfx950 16x16x32 bf16): A[m=lane&15][k=quad*8+j],
// B[k=quad*8+j][n=lane&15], D col=lane&15, row=quad*4+reg. ----------------
__global__ __launch_bounds__(256) void k_gemm(const ushort_t* __restrict__ x,
                                              const ushort_t* __restrict__ wbt,
                                              const float* __restrict__ bias,
                                              ushort_t* __restrict__ y,
                                              float* __restrict__ bnsum,
                                              float* __restrict__ bnsq) {
    __shared__ ushort_t bs[2048 * 8];  // 32 KB: frag f=(k0b*8+nb)*64+lane, 8 bf16 each
    __shared__ float csum[DIM];
    __shared__ float csq[DIM];
    // stage B: 2048 fragments, 8 per thread
#pragma unroll
    for (int i = 0; i < 8; ++i) {
        int f = threadIdx.x + i * 256;
        int fm16 = f & 15;
        int fquad = (f >> 4) & 3;
        int fnb = (f >> 6) & 7;
        int fk0b = f >> 9;
        int ncol = fnb * 16 + fm16;
        *(uint4*)&bs[f * 8] = *(const uint4*)(wbt + (size_t)ncol * DIM + fk0b * 32 + fquad * 8);
    }
    if (threadIdx.x < DIM) { csum[threadIdx.x] = 0.f; csq[threadIdx.x] = 0.f; }
    __syncthreads();

    int wave = threadIdx.x >> 6;   // 0..3
    int lane = threadIdx.x & 63;
    int m16 = lane & 15;
    int quad = lane >> 4;          // 0..3
    int row0 = blockIdx.x * 64 + wave * 16;

    f32x4 acc[8];
#pragma unroll
    for (int nb = 0; nb < 8; ++nb) acc[nb] = (f32x4)(0.f);

    int arow = row0 + m16;
    bool rowok = arow < N_NODES;
    const ushort_t* xp = x + (size_t)arow * DIM + quad * 8;

#pragma unroll
    for (int k0b = 0; k0b < 4; ++k0b) {
        bf16x8 af;
        if (rowok) af = *(const bf16x8*)(xp + k0b * 32);
        else af = (bf16x8)(short)0;
#pragma unroll
        for (int nb = 0; nb < 8; ++nb) {
            bf16x8 bfg = *(const bf16x8*)&bs[(((k0b * 8 + nb) << 6) + lane) * 8];
            acc[nb] = __builtin_amdgcn_mfma_f32_16x16x32_bf16(af, bfg, acc[nb], 0, 0, 0);
        }
    }

    // epilogue: bias, BN partial stats, bf16 store
#pragma unroll
    for (int nb = 0; nb < 8; ++nb) {
        int col = nb * 16 + m16;
        float bcol = bias[col];
        float ps = 0.f, pq = 0.f;
#pragma unroll
        for (int reg = 0; reg < 4; ++reg) {
            int r = row0 + quad * 4 + reg;
            if (r < N_NODES) {
                float v = acc[nb][reg] + bcol;
                ps += v; pq += v * v;
                y[(size_t)r * DIM + col] = f2bf(v);
            }
        }
        atomicAdd(&csum[col], ps);
        atomicAdd(&csq[col], pq);
    }
    __syncthreads();
    if (threadIdx.x < DIM) {
        atomicAdd(&bnsum[threadIdx.x], csum[threadIdx.x]);
        atomicAdd(&bnsq[threadIdx.x], csq[threadIdx.x]);
    }
}

// ---------------- BN fold ----------------
__global__ void k_bnfold(const float* __restrict__ sum, const float* __restrict__ sumsq,
                         const float* __restrict__ g, const float* __restrict__ be,
                         float* __restrict__ bna, float* __restrict__ bnc) {
    int c = threadIdx.x;  // 128
    float mu = sum[c] * (1.0f / N_NODES);
    float var = sumsq[c] * (1.0f / N_NODES) - mu * mu;
    float rstd = rsqrtf(var + BN_EPS);
    float a = g[c] * rstd;
    bna[c] = a;
    bnc[c] = be[c] - mu * a;
}

// ---------------- BN apply + relu + norm_src prescale, bf16 in/out ----------------
__global__ void k_bnapply(const ushort_t* __restrict__ yin, ushort_t* __restrict__ xout,
                          const float* __restrict__ bna, const float* __restrict__ bnc,
                          const float* __restrict__ scale) {
    int gid = blockIdx.x * blockDim.x + threadIdx.x;  // N*16
    int node = gid >> 4;
    int sub = gid & 15;
    if (node >= N_NODES) return;
    float s = scale[node];
    uint4 u = *(const uint4*)(yin + (size_t)node * DIM + sub * 8);
    float v[8] = {bfl(u.x), bfh(u.x), bfl(u.y), bfh(u.y),
                  bfl(u.z), bfh(u.z), bfl(u.w), bfh(u.w)};
    const float* a = bna + sub * 8;
    const float* c = bnc + sub * 8;
#pragma unroll
    for (int i = 0; i < 8; ++i) v[i] = fmaxf(v[i] * a[i] + c[i], 0.f) * s;
    uint4 o;
    o.x = pack2(v[0], v[1]); o.y = pack2(v[2], v[3]);
    o.z = pack2(v[4], v[5]); o.w = pack2(v[6], v[7]);
    *(uint4*)(xout + (size_t)node * DIM + sub * 8) = o;
}

// ---------------- pooling ----------------
__global__ void k_poolcnt(const int* __restrict__ gids, int* __restrict__ cnt) {
    __shared__ int h[N_GRAPHS];
    if (threadIdx.x < N_GRAPHS) h[threadIdx.x] = 0;
    __syncthreads();
    int i = blockIdx.x * blockDim.x + threadIdx.x;
    if (i < N_NODES) atomicAdd(&h[gids[i]], 1);
    __syncthreads();
    if (threadIdx.x < N_GRAPHS) {
        int v = h[threadIdx.x];
        if (v) atomicAdd(&cnt[threadIdx.x], v);
    }
}

// ---------------- pooling with fused layer-3 BN+relu ----------------
#define POOL_NODES 256
__global__ void k_poolsum_bn(const ushort_t* __restrict__ yin, const int* __restrict__ gids,
                             const float* __restrict__ bna, const float* __restrict__ bnc,
                             float* __restrict__ pool) {
    int col = threadIdx.x;  // 128
    float a = bna[col];
    float c = bnc[col];
    int base = blockIdx.x * POOL_NODES;
    if (base >= N_NODES) return;
    int end = min(base + POOL_NODES, N_NODES);
    float acc = 0.f;
    int cur = gids[base];
    for (int n = base; n < end; ++n) {
        int g = gids[n];
        if (g != cur) {
            atomicAdd(&pool[(size_t)cur * DIM + col], acc);
            acc = 0.f;
            cur = g;
        }
        uint_t u = *(const uint_t*)(yin + (size_t)n * DIM + (col & ~1));
        float v = (col & 1) ? bfh(u) : bfl(u);
        acc += fmaxf(v * a + c, 0.f);
    }
    atomicAdd(&pool[(size_t)cur * DIM + col], acc);
}

// ---------------- final FC (one block per graph) ----------------
__global__ void k_final(const float* __restrict__ pool, const int* __restrict__ cnt,
                        const float* __restrict__ fcW1, const float* __restrict__ fcb1,
                        const float* __restrict__ fcW2, const float* __restrict__ fcb2,
                        float* __restrict__ out) {
    __shared__ float hg[DIM];
    __shared__ float z[64];
    int g = blockIdx.x;
    int t = threadIdx.x;  // 128
    float cf = fmaxf((float)cnt[g], 1.0f);
    hg[t] = pool[(size_t)g * DIM + t] / cf;
    __syncthreads();
    if (t < 64) {
        float acc = fcb1[t];
        for (int k = 0; k < DIM; ++k)
            acc += hg[k] * fcW1[k * 64 + t];
        z[t] = fmaxf(acc, 0.f);
    }
    __syncthreads();
    if (t < 2) {
        float acc = fcb2[t];
        for (int k = 0; k < 64; ++k)
            acc += z[k] * fcW2[k * 2 + t];
        out[g * 2 + t] = acc;
    }
}

extern "C" void kernel_launch(void* const* d_in, const int* in_sizes, int n_in,
                              void* d_out, int out_size, void* d_ws, size_t ws_size,
                              hipStream_t stream) {
    const int* tokens = (const int*)d_in[0];
    const int* src = (const int*)d_in[1];
    const int* dst = (const int*)d_in[2];
    const int* gids = (const int*)d_in[3];
    const float* embed = (const float*)d_in[4];
    const float* W1 = (const float*)d_in[5];
    const float* b1 = (const float*)d_in[6];
    const float* g1 = (const float*)d_in[7];
    const float* be1 = (const float*)d_in[8];
    const float* W2 = (const float*)d_in[9];
    const float* b2 = (const float*)d_in[10];
    const float* g2 = (const float*)d_in[11];
    const float* be2 = (const float*)d_in[12];
    const float* W3 = (const float*)d_in[13];
    const float* b3 = (const float*)d_in[14];
    const float* g3 = (const float*)d_in[15];
    const float* be3 = (const float*)d_in[16];
    const float* fcW1 = (const float*)d_in[17];
    const float* fcb1 = (const float*)d_in[18];
    const float* fcW2 = (const float*)d_in[19];
    const float* fcb2 = (const float*)d_in[20];
    float* out = (float*)d_out;

    char* w = (char*)d_ws;
    auto alloc = [&](size_t bytes) {
        void* p = (void*)w;
        w += (bytes + 255) & ~(size_t)255;
        return p;
    };
    // bf16 feature buffers; bufX has a sentinel zero row at index N_NODES
    ushort_t* bufX = (ushort_t*)alloc((size_t)(N_NODES + 1) * DIM * 2);
    ushort_t* bufAgg = (ushort_t*)alloc((size_t)N_NODES * DIM * 2);
    ushort_t* bufY = (ushort_t*)alloc((size_t)N_NODES * DIM * 2);
    int* esrc = (int*)alloc((size_t)EPAD * 4);
    ushort_t* pos = (ushort_t*)alloc((size_t)N_EDGES * 2);
    int* rowptr = (int*)alloc((size_t)(N_NODES + 1) * 4);
    float* ns = (float*)alloc((size_t)N_NODES * 4);
    float* nd = (float*)alloc((size_t)N_NODES * 4);
    float* bna = (float*)alloc(3 * DIM * 4);
    float* bnc = (float*)alloc(3 * DIM * 4);
    int* partials = (int*)alloc(1024 * 4);
    ushort_t* wbt = (ushort_t*)alloc(3 * DIM * DIM * 2);
    // zeroed region (contiguous)
    char* zstart = w;
    int* dego = (int*)alloc((size_t)N_NODES * 4);
    int* degi = (int*)alloc((size_t)N_NODES * 4);
    float* bnsum = (float*)alloc(3 * DIM * 4);
    float* bnsq = (float*)alloc(3 * DIM * 4);
    float* pool = (float*)alloc((size_t)N_GRAPHS * DIM * 4);
    int* cnt = (int*)alloc((size_t)N_GRAPHS * 4);
    int zwords = (int)((size_t)(w - zstart) / 4);

    int nb_e = (N_EDGES + 255) / 256;
    int nb_n = (N_NODES + 255) / 256;
    int nb_scan = (N_NODES + SCAN_B - 1) / SCAN_B;

    k_zero<<<(zwords + 255) / 256, 256, 0, stream>>>((int*)zstart, zwords);
    k_sent<<<(EPAD + 255) / 256, 256, 0, stream>>>(esrc, bufX);
    k_degpos<<<nb_e, 256, 0, stream>>>(src, dst, dego, degi, pos);
    k_norms<<<nb_n, 256, 0, stream>>>(dego, degi, ns, nd);
    k_scan1<<<nb_scan, SCAN_B, 0, stream>>>(degi, rowptr, partials);
    k_scan2<<<1, SCAN2_T, 0, stream>>>(partials, rowptr, nb_scan);
    k_scan3<<<nb_scan, SCAN_B, 0, stream>>>(partials, rowptr);
    k_scatter<<<nb_e, 256, 0, stream>>>(src, dst, rowptr, pos, esrc);
    k_wprep<<<(3 * DIM * DIM + 255) / 256, 256, 0, stream>>>(W1, W2, W3, wbt);
    k_embed<<<(N_NODES * 16 + 255) / 256, 256, 0, stream>>>(tokens, embed, ns, bufX);

    const float* bias_l[3] = {b1, b2, b3};
    const float* g_l[3] = {g1, g2, g3};
    const float* be_l[3] = {be1, be2, be3};
    int nb_agg = (N_NODES * 64 + 255) / 256;
    int nb_gemm = (N_NODES + 63) / 64;
    int nb_el = (N_NODES * 16 + 255) / 256;

    for (int l = 0; l < 3; ++l) {
        k_aggregate<<<nb_agg, 256, 0, stream>>>(bufX, rowptr, esrc, nd, bufAgg);
        k_gemm<<<nb_gemm, 256, 0, stream>>>(bufAgg, wbt + (size_t)l * DIM * DIM, bias_l[l],
                                            bufY, bnsum + l * DIM, bnsq + l * DIM);
        k_bnfold<<<1, DIM, 0, stream>>>(bnsum + l * DIM, bnsq + l * DIM, g_l[l], be_l[l],
                                        bna + l * DIM, bnc + l * DIM);
        if (l < 2)
            k_bnapply<<<nb_el, 256, 0, stream>>>(bufY, bufX, bna + l * DIM, bnc + l * DIM, ns);
    }

    k_poolcnt<<<nb_n, 256, 0, stream>>>(gids, cnt);
    k_poolsum_bn<<<(N_NODES + POOL_NODES - 1) / POOL_NODES, DIM, 0, stream>>>(
        bufY, gids, bna + 2 * DIM, bnc + 2 * DIM, pool);
    k_final<<<N_GRAPHS, DIM, 0, stream>>>(pool, cnt, fcW1, fcb1, fcW2, fcb2, out);
}

// Round 9
// 758.137 us; speedup vs baseline: 2.6002x; 1.0235x over previous
//
#include <hip/hip_runtime.h>

#define N_NODES 100000
#define N_EDGES 1600000
#define N_GRAPHS 64
#define DIM 128
#define BN_EPS 1e-5f
#define EPAD (N_EDGES + 4 * N_NODES)

#define NB_DEG 6250   // 6250*256 = 1.6M edges
#define NB_EMB 6250   // 100k nodes * 16 thr
#define NB_SENT 977   // EPAD/(256*8)
#define NB_WPREP 192  // 3*128*128/256

typedef unsigned short ushort_t;
typedef unsigned int uint_t;
typedef __attribute__((ext_vector_type(8))) short bf16x8;
typedef __attribute__((ext_vector_type(4))) float f32x4;

__device__ __forceinline__ float bfl(uint_t u) {
    union { uint_t i; float f; } v; v.i = u << 16; return v.f;
}
__device__ __forceinline__ float bfh(uint_t u) {
    union { uint_t i; float f; } v; v.i = u & 0xffff0000u; return v.f;
}
__device__ __forceinline__ ushort_t f2bf(float f) {
    union { float f; uint_t i; } v; v.f = f;
    uint_t x = v.i;
    return (ushort_t)((x + 0x7fffu + ((x >> 16) & 1u)) >> 16);
}
__device__ __forceinline__ uint_t pack2(float lo, float hi) {
    return ((uint_t)f2bf(hi) << 16) | (uint_t)f2bf(lo);
}

// ---------------- zero scratch ----------------
__global__ void k_zero(int* __restrict__ p, int n) {
    int i = blockIdx.x * blockDim.x + threadIdx.x;
    if (i < n) p[i] = 0;
}

// ---------------- front mega-kernel: {degpos | embed | sentinel | wprep} ----------------
// degpos is TCC-atomic bound with idle CUs; the other partitions ride free.
__global__ void k_front(const int* __restrict__ src, const int* __restrict__ dst,
                        int* __restrict__ dego, int* __restrict__ degi,
                        ushort_t* __restrict__ pos,
                        const int* __restrict__ tokens, const float* __restrict__ embed,
                        ushort_t* __restrict__ bufH, ushort_t* __restrict__ bufY,
                        int* __restrict__ esrc,
                        const float* __restrict__ w1, const float* __restrict__ w2,
                        const float* __restrict__ w3, ushort_t* __restrict__ wbt) {
    int b = blockIdx.x;
    int t = threadIdx.x;
    if (b < NB_DEG) {
        int e = b * 256 + t;
        if (e < N_EDGES) {
            atomicAdd(&dego[src[e]], 1);
            int p = atomicAdd(&degi[dst[e]], 1);
            pos[e] = (ushort_t)p;
        }
        return;
    }
    b -= NB_DEG;
    if (b < NB_EMB) {  // raw embedding gather (no ns prescale — ns applied in aggbn)
        int gid = b * 256 + t;
        int node = gid >> 4, sub = gid & 15;
        const float* ep = embed + (size_t)tokens[node] * DIM + sub * 8;
        float4 a = *(const float4*)ep;
        float4 c = *(const float4*)(ep + 4);
        uint4 o;
        o.x = pack2(a.x, a.y); o.y = pack2(a.z, a.w);
        o.z = pack2(c.x, c.y); o.w = pack2(c.z, c.w);
        *(uint4*)(bufH + (size_t)node * DIM + sub * 8) = o;
        return;
    }
    b -= NB_EMB;
    if (b < NB_SENT) {  // esrc sentinel fill + zero sentinel feature rows
        int i0 = (b * 256 + t) * 8;
        int4 sv = make_int4(N_NODES, N_NODES, N_NODES, N_NODES);
        if (i0 + 8 <= EPAD) {
            *(int4*)(esrc + i0) = sv;
            *(int4*)(esrc + i0 + 4) = sv;
        } else {
            for (int i = i0; i < EPAD; ++i) esrc[i] = N_NODES;
        }
        if (b == 0 && t < 64) {
            ((uint_t*)(bufH + (size_t)N_NODES * DIM))[t] = 0u;
            ((uint_t*)(bufY + (size_t)N_NODES * DIM))[t] = 0u;
        }
        return;
    }
    b -= NB_SENT;
    {  // W fp32 [k][n] -> bf16 transposed [n][k]
        int i = b * 256 + t;
        int l = i >> 14;
        int idx = i & (DIM * DIM - 1);
        int n = idx >> 7, k = idx & (DIM - 1);
        const float* wsrc = (l == 0) ? w1 : (l == 1) ? w2 : w3;
        wbt[i] = f2bf(wsrc[k * DIM + n]);
    }
}

// ---------------- scan (rowptr from padded deg_in) + norms fused ----------------
#define SCAN_B 256
__global__ void k_scan1(const int* __restrict__ dego, const int* __restrict__ degi,
                        int* __restrict__ rowptr, int* __restrict__ partials,
                        float* __restrict__ ns, float* __restrict__ nd) {
    __shared__ int s[SCAN_B];
    int t = threadIdx.x;
    int i = blockIdx.x * SCAN_B + t;
    int d = (i < N_NODES) ? degi[i] : 0;
    int v = (d + 3) & ~3;  // pad rows to multiple of 4
    s[t] = v;
    __syncthreads();
    for (int off = 1; off < SCAN_B; off <<= 1) {
        int add = (t >= off) ? s[t - off] : 0;
        __syncthreads();
        s[t] += add;
        __syncthreads();
    }
    if (i < N_NODES) {
        rowptr[i + 1] = s[t];
        ns[i] = rsqrtf(fmaxf((float)dego[i], 1.0f));
        nd[i] = rsqrtf(fmaxf((float)d, 1.0f));
    }
    if (blockIdx.x == 0 && t == 0) ns[N_NODES] = 0.f;  // kills sentinel contributions
    if (t == SCAN_B - 1) partials[blockIdx.x] = s[t];
}

#define SCAN2_T 512
__global__ void k_scan2(int* __restrict__ partials, int* __restrict__ rowptr, int nb) {
    __shared__ int s[SCAN2_T];
    int t = threadIdx.x;
    int v = (t < nb) ? partials[t] : 0;
    s[t] = v;
    __syncthreads();
    for (int off = 1; off < SCAN2_T; off <<= 1) {
        int add = (t >= off) ? s[t - off] : 0;
        __syncthreads();
        s[t] += add;
        __syncthreads();
    }
    if (t < nb) partials[t] = s[t] - v;  // exclusive
    if (t == 0) rowptr[0] = 0;
}

__global__ void k_scan3(const int* __restrict__ partials, int* __restrict__ rowptr) {
    int i = blockIdx.x * SCAN_B + threadIdx.x;
    if (i < N_NODES) rowptr[i + 1] += partials[blockIdx.x];
}

// ---------------- CSR scatter (atomic-free) ----------------
__global__ void k_scatter(const int* __restrict__ src, const int* __restrict__ dst,
                          const int* __restrict__ rowptr, const ushort_t* __restrict__ pos,
                          int* __restrict__ esrc) {
    int e = blockIdx.x * blockDim.x + threadIdx.x;
    if (e < N_EDGES) {
        int d = dst[e];
        esrc[rowptr[d] + (int)pos[e]] = src[e];
    }
}

// ---------------- aggregation with fused BN+relu+ns (DOBN=0: l0, plain h*ns) ----------------
template <int DOBN>
__global__ __launch_bounds__(256) void k_aggbn(const ushort_t* __restrict__ hs,
        const int* __restrict__ rowptr, const int* __restrict__ esrc,
        const float* __restrict__ ns, const float* __restrict__ nd,
        const float* __restrict__ bnsum, const float* __restrict__ bnsq,
        const float* __restrict__ g, const float* __restrict__ be,
        ushort_t* __restrict__ agg) {
    __shared__ float sa[DIM], sc[DIM];
    int tid = threadIdx.x;
    if (DOBN) {
        if (tid < DIM) {
            float mu = bnsum[tid] * (1.0f / N_NODES);
            float var = bnsq[tid] * (1.0f / N_NODES) - mu * mu;
            float rstd = rsqrtf(var + BN_EPS);
            float a = g[tid] * rstd;
            sa[tid] = a;
            sc[tid] = be[tid] - mu * a;
        }
        __syncthreads();
    }
    int wid = (blockIdx.x * 256 + tid) >> 6;
    int lane = tid & 63;
    if (wid >= N_NODES) return;
    float a0 = 0.f, a1 = 0.f, c0 = 0.f, c1 = 0.f;
    if (DOBN) { a0 = sa[lane * 2]; a1 = sa[lane * 2 + 1]; c0 = sc[lane * 2]; c1 = sc[lane * 2 + 1]; }
    int beg = rowptr[wid], end = rowptr[wid + 1];
    int off = lane * 2;
    float ax0 = 0.f, ay0 = 0.f, ax1 = 0.f, ay1 = 0.f;
    float ax2 = 0.f, ay2 = 0.f, ax3 = 0.f, ay3 = 0.f;
    int e = beg;
    for (; e + 8 <= end; e += 8) {
        int4 i0 = *(const int4*)(esrc + e);
        int4 i1 = *(const int4*)(esrc + e + 4);
        uint_t u0 = *(const uint_t*)(hs + (size_t)i0.x * DIM + off);
        uint_t u1 = *(const uint_t*)(hs + (size_t)i0.y * DIM + off);
        uint_t u2 = *(const uint_t*)(hs + (size_t)i0.z * DIM + off);
        uint_t u3 = *(const uint_t*)(hs + (size_t)i0.w * DIM + off);
        uint_t u4 = *(const uint_t*)(hs + (size_t)i1.x * DIM + off);
        uint_t u5 = *(const uint_t*)(hs + (size_t)i1.y * DIM + off);
        uint_t u6 = *(const uint_t*)(hs + (size_t)i1.z * DIM + off);
        uint_t u7 = *(const uint_t*)(hs + (size_t)i1.w * DIM + off);
        float n0 = ns[i0.x], n1 = ns[i0.y], n2 = ns[i0.z], n3 = ns[i0.w];
        float n4 = ns[i1.x], n5 = ns[i1.y], n6 = ns[i1.z], n7 = ns[i1.w];
        float v0l = bfl(u0), v0h = bfh(u0), v1l = bfl(u1), v1h = bfh(u1);
        float v2l = bfl(u2), v2h = bfh(u2), v3l = bfl(u3), v3h = bfh(u3);
        float v4l = bfl(u4), v4h = bfh(u4), v5l = bfl(u5), v5h = bfh(u5);
        float v6l = bfl(u6), v6h = bfh(u6), v7l = bfl(u7), v7h = bfh(u7);
        if (DOBN) {
            v0l = fmaxf(fmaf(v0l, a0, c0), 0.f); v0h = fmaxf(fmaf(v0h, a1, c1), 0.f);
            v1l = fmaxf(fmaf(v1l, a0, c0), 0.f); v1h = fmaxf(fmaf(v1h, a1, c1), 0.f);
            v2l = fmaxf(fmaf(v2l, a0, c0), 0.f); v2h = fmaxf(fmaf(v2h, a1, c1), 0.f);
            v3l = fmaxf(fmaf(v3l, a0, c0), 0.f); v3h = fmaxf(fmaf(v3h, a1, c1), 0.f);
            v4l = fmaxf(fmaf(v4l, a0, c0), 0.f); v4h = fmaxf(fmaf(v4h, a1, c1), 0.f);
            v5l = fmaxf(fmaf(v5l, a0, c0), 0.f); v5h = fmaxf(fmaf(v5h, a1, c1), 0.f);
            v6l = fmaxf(fmaf(v6l, a0, c0), 0.f); v6h = fmaxf(fmaf(v6h, a1, c1), 0.f);
            v7l = fmaxf(fmaf(v7l, a0, c0), 0.f); v7h = fmaxf(fmaf(v7h, a1, c1), 0.f);
        }
        ax0 = fmaf(v0l, n0, ax0); ay0 = fmaf(v0h, n0, ay0);
        ax1 = fmaf(v1l, n1, ax1); ay1 = fmaf(v1h, n1, ay1);
        ax2 = fmaf(v2l, n2, ax2); ay2 = fmaf(v2h, n2, ay2);
        ax3 = fmaf(v3l, n3, ax3); ay3 = fmaf(v3h, n3, ay3);
        ax0 = fmaf(v4l, n4, ax0); ay0 = fmaf(v4h, n4, ay0);
        ax1 = fmaf(v5l, n5, ax1); ay1 = fmaf(v5h, n5, ay1);
        ax2 = fmaf(v6l, n6, ax2); ay2 = fmaf(v6h, n6, ay2);
        ax3 = fmaf(v7l, n7, ax3); ay3 = fmaf(v7h, n7, ay3);
    }
    if (e < end) {  // remaining 4 (rows padded to multiple of 4)
        int4 i0 = *(const int4*)(esrc + e);
        uint_t u0 = *(const uint_t*)(hs + (size_t)i0.x * DIM + off);
        uint_t u1 = *(const uint_t*)(hs + (size_t)i0.y * DIM + off);
        uint_t u2 = *(const uint_t*)(hs + (size_t)i0.z * DIM + off);
        uint_t u3 = *(const uint_t*)(hs + (size_t)i0.w * DIM + off);
        float n0 = ns[i0.x], n1 = ns[i0.y], n2 = ns[i0.z], n3 = ns[i0.w];
        float v0l = bfl(u0), v0h = bfh(u0), v1l = bfl(u1), v1h = bfh(u1);
        float v2l = bfl(u2), v2h = bfh(u2), v3l = bfl(u3), v3h = bfh(u3);
        if (DOBN) {
            v0l = fmaxf(fmaf(v0l, a0, c0), 0.f); v0h = fmaxf(fmaf(v0h, a1, c1), 0.f);
            v1l = fmaxf(fmaf(v1l, a0, c0), 0.f); v1h = fmaxf(fmaf(v1h, a1, c1), 0.f);
            v2l = fmaxf(fmaf(v2l, a0, c0), 0.f); v2h = fmaxf(fmaf(v2h, a1, c1), 0.f);
            v3l = fmaxf(fmaf(v3l, a0, c0), 0.f); v3h = fmaxf(fmaf(v3h, a1, c1), 0.f);
        }
        ax0 = fmaf(v0l, n0, ax0); ay0 = fmaf(v0h, n0, ay0);
        ax1 = fmaf(v1l, n1, ax1); ay1 = fmaf(v1h, n1, ay1);
        ax2 = fmaf(v2l, n2, ax2); ay2 = fmaf(v2h, n2, ay2);
        ax3 = fmaf(v3l, n3, ax3); ay3 = fmaf(v3h, n3, ay3);
    }
    float ax = (ax0 + ax1) + (ax2 + ax3);
    float ay = (ay0 + ay1) + (ay2 + ay3);
    float n = nd[wid];
    *(uint_t*)(agg + (size_t)wid * DIM + off) = pack2(ax * n, ay * n);
}

// ---------------- MFMA GEMM + fused BN stats, B staged in LDS fragment-order ----------------
__global__ __launch_bounds__(256) void k_gemm(const ushort_t* __restrict__ x,
                                              const ushort_t* __restrict__ wbt,
                                              const float* __restrict__ bias,
                                              ushort_t* __restrict__ y,
                                              float* __restrict__ bnsum,
                                              float* __restrict__ bnsq) {
    __shared__ ushort_t bs[2048 * 8];
    __shared__ float csum[DIM];
    __shared__ float csq[DIM];
#pragma unroll
    for (int i = 0; i < 8; ++i) {
        int f = threadIdx.x + i * 256;
        int fm16 = f & 15;
        int fquad = (f >> 4) & 3;
        int fnb = (f >> 6) & 7;
        int fk0b = f >> 9;
        int ncol = fnb * 16 + fm16;
        *(uint4*)&bs[f * 8] = *(const uint4*)(wbt + (size_t)ncol * DIM + fk0b * 32 + fquad * 8);
    }
    if (threadIdx.x < DIM) { csum[threadIdx.x] = 0.f; csq[threadIdx.x] = 0.f; }
    __syncthreads();

    int wave = threadIdx.x >> 6;
    int lane = threadIdx.x & 63;
    int m16 = lane & 15;
    int quad = lane >> 4;
    int row0 = blockIdx.x * 64 + wave * 16;

    f32x4 acc[8];
#pragma unroll
    for (int nb = 0; nb < 8; ++nb) acc[nb] = (f32x4)(0.f);

    int arow = row0 + m16;
    bool rowok = arow < N_NODES;
    const ushort_t* xp = x + (size_t)arow * DIM + quad * 8;

#pragma unroll
    for (int k0b = 0; k0b < 4; ++k0b) {
        bf16x8 af;
        if (rowok) af = *(const bf16x8*)(xp + k0b * 32);
        else af = (bf16x8)(short)0;
#pragma unroll
        for (int nb = 0; nb < 8; ++nb) {
            bf16x8 bfg = *(const bf16x8*)&bs[(((k0b * 8 + nb) << 6) + lane) * 8];
            acc[nb] = __builtin_amdgcn_mfma_f32_16x16x32_bf16(af, bfg, acc[nb], 0, 0, 0);
        }
    }

#pragma unroll
    for (int nb = 0; nb < 8; ++nb) {
        int col = nb * 16 + m16;
        float bcol = bias[col];
        float ps = 0.f, pq = 0.f;
#pragma unroll
        for (int reg = 0; reg < 4; ++reg) {
            int r = row0 + quad * 4 + reg;
            if (r < N_NODES) {
                float v = acc[nb][reg] + bcol;
                ps += v; pq += v * v;
                y[(size_t)r * DIM + col] = f2bf(v);
            }
        }
        atomicAdd(&csum[col], ps);
        atomicAdd(&csq[col], pq);
    }
    __syncthreads();
    if (threadIdx.x < DIM) {
        atomicAdd(&bnsum[threadIdx.x], csum[threadIdx.x]);
        atomicAdd(&bnsq[threadIdx.x], csq[threadIdx.x]);
    }
}

// ---------------- pooling: fused layer-3 BN fold+apply + graph counts ----------------
#define POOL_NODES 256
__global__ void k_pool(const ushort_t* __restrict__ yin, const int* __restrict__ gids,
                       const float* __restrict__ bnsum, const float* __restrict__ bnsq,
                       const float* __restrict__ g, const float* __restrict__ be,
                       float* __restrict__ pool, int* __restrict__ cnt) {
    __shared__ int h[N_GRAPHS];
    int col = threadIdx.x;  // 128
    float mu = bnsum[col] * (1.0f / N_NODES);
    float var = bnsq[col] * (1.0f / N_NODES) - mu * mu;
    float rstd = rsqrtf(var + BN_EPS);
    float a = g[col] * rstd;
    float c = be[col] - mu * a;
    if (col < N_GRAPHS) h[col] = 0;
    __syncthreads();
    int base = blockIdx.x * POOL_NODES;
    int end = min(base + POOL_NODES, N_NODES);
    for (int n = base + col; n < end; n += 128) atomicAdd(&h[gids[n]], 1);
    __syncthreads();
    if (col < N_GRAPHS && h[col]) atomicAdd(&cnt[col], h[col]);
    float acc = 0.f;
    int cur = gids[base];
    for (int n = base; n < end; ++n) {
        int gg = gids[n];
        if (gg != cur) {
            atomicAdd(&pool[(size_t)cur * DIM + col], acc);
            acc = 0.f;
            cur = gg;
        }
        uint_t u = *(const uint_t*)(yin + (size_t)n * DIM + (col & ~1));
        float v = (col & 1) ? bfh(u) : bfl(u);
        acc += fmaxf(fmaf(v, a, c), 0.f);
    }
    atomicAdd(&pool[(size_t)cur * DIM + col], acc);
}

// ---------------- final FC (one block per graph) ----------------
__global__ void k_final(const float* __restrict__ pool, const int* __restrict__ cnt,
                        const float* __restrict__ fcW1, const float* __restrict__ fcb1,
                        const float* __restrict__ fcW2, const float* __restrict__ fcb2,
                        float* __restrict__ out) {
    __shared__ float hg[DIM];
    __shared__ float z[64];
    int g = blockIdx.x;
    int t = threadIdx.x;  // 128
    float cf = fmaxf((float)cnt[g], 1.0f);
    hg[t] = pool[(size_t)g * DIM + t] / cf;
    __syncthreads();
    if (t < 64) {
        float acc = fcb1[t];
        for (int k = 0; k < DIM; ++k)
            acc += hg[k] * fcW1[k * 64 + t];
        z[t] = fmaxf(acc, 0.f);
    }
    __syncthreads();
    if (t < 2) {
        float acc = fcb2[t];
        for (int k = 0; k < 64; ++k)
            acc += z[k] * fcW2[k * 2 + t];
        out[g * 2 + t] = acc;
    }
}

extern "C" void kernel_launch(void* const* d_in, const int* in_sizes, int n_in,
                              void* d_out, int out_size, void* d_ws, size_t ws_size,
                              hipStream_t stream) {
    const int* tokens = (const int*)d_in[0];
    const int* src = (const int*)d_in[1];
    const int* dst = (const int*)d_in[2];
    const int* gids = (const int*)d_in[3];
    const float* embed = (const float*)d_in[4];
    const float* W1 = (const float*)d_in[5];
    const float* b1 = (const float*)d_in[6];
    const float* g1 = (const float*)d_in[7];
    const float* be1 = (const float*)d_in[8];
    const float* W2 = (const float*)d_in[9];
    const float* b2 = (const float*)d_in[10];
    const float* g2 = (const float*)d_in[11];
    const float* be2 = (const float*)d_in[12];
    const float* W3 = (const float*)d_in[13];
    const float* b3 = (const float*)d_in[14];
    const float* g3 = (const float*)d_in[15];
    const float* be3 = (const float*)d_in[16];
    const float* fcW1 = (const float*)d_in[17];
    const float* fcb1 = (const float*)d_in[18];
    const float* fcW2 = (const float*)d_in[19];
    const float* fcb2 = (const float*)d_in[20];
    float* out = (float*)d_out;

    char* w = (char*)d_ws;
    auto alloc = [&](size_t bytes) {
        void* p = (void*)w;
        w += (bytes + 255) & ~(size_t)255;
        return p;
    };
    ushort_t* bufH = (ushort_t*)alloc((size_t)(N_NODES + 1) * DIM * 2);  // embed out (raw)
    ushort_t* bufY = (ushort_t*)alloc((size_t)(N_NODES + 1) * DIM * 2);  // gemm out (pre-BN)
    ushort_t* bufAgg = (ushort_t*)alloc((size_t)N_NODES * DIM * 2);      // aggregate out
    int* esrc = (int*)alloc((size_t)EPAD * 4);
    ushort_t* pos = (ushort_t*)alloc((size_t)N_EDGES * 2);
    int* rowptr = (int*)alloc((size_t)(N_NODES + 1) * 4);
    float* ns = (float*)alloc((size_t)(N_NODES + 1) * 4);
    float* nd = (float*)alloc((size_t)N_NODES * 4);
    int* partials = (int*)alloc(1024 * 4);
    ushort_t* wbt = (ushort_t*)alloc(3 * DIM * DIM * 2);
    // zeroed region (contiguous)
    char* zstart = w;
    int* dego = (int*)alloc((size_t)N_NODES * 4);
    int* degi = (int*)alloc((size_t)N_NODES * 4);
    float* bnsum = (float*)alloc(3 * DIM * 4);
    float* bnsq = (float*)alloc(3 * DIM * 4);
    float* pool = (float*)alloc((size_t)N_GRAPHS * DIM * 4);
    int* cnt = (int*)alloc((size_t)N_GRAPHS * 4);
    int zwords = (int)((size_t)(w - zstart) / 4);

    int nb_e = (N_EDGES + 255) / 256;
    int nb_scan = (N_NODES + SCAN_B - 1) / SCAN_B;

    k_zero<<<(zwords + 255) / 256, 256, 0, stream>>>((int*)zstart, zwords);
    k_front<<<NB_DEG + NB_EMB + NB_SENT + NB_WPREP, 256, 0, stream>>>(
        src, dst, dego, degi, pos, tokens, embed, bufH, bufY, esrc, W1, W2, W3, wbt);
    k_scan1<<<nb_scan, SCAN_B, 0, stream>>>(dego, degi, rowptr, partials, ns, nd);
    k_scan2<<<1, SCAN2_T, 0, stream>>>(partials, rowptr, nb_scan);
    k_scan3<<<nb_scan, SCAN_B, 0, stream>>>(partials, rowptr);
    k_scatter<<<nb_e, 256, 0, stream>>>(src, dst, rowptr, pos, esrc);

    const float* bias_l[3] = {b1, b2, b3};
    const float* g_l[3] = {g1, g2, g3};
    const float* be_l[3] = {be1, be2, be3};
    int nb_agg = (N_NODES * 64 + 255) / 256;
    int nb_gemm = (N_NODES + 63) / 64;

    for (int l = 0; l < 3; ++l) {
        const ushort_t* hs_in = (l == 0) ? bufH : bufY;
        if (l == 0)
            k_aggbn<0><<<nb_agg, 256, 0, stream>>>(hs_in, rowptr, esrc, ns, nd,
                                                   nullptr, nullptr, nullptr, nullptr, bufAgg);
        else
            k_aggbn<1><<<nb_agg, 256, 0, stream>>>(hs_in, rowptr, esrc, ns, nd,
                                                   bnsum + (l - 1) * DIM, bnsq + (l - 1) * DIM,
                                                   g_l[l - 1], be_l[l - 1], bufAgg);
        k_gemm<<<nb_gemm, 256, 0, stream>>>(bufAgg, wbt + (size_t)l * DIM * DIM, bias_l[l],
                                            bufY, bnsum + l * DIM, bnsq + l * DIM);
    }

    k_pool<<<(N_NODES + POOL_NODES - 1) / POOL_NODES, DIM, 0, stream>>>(
        bufY, gids, bnsum + 2 * DIM, bnsq + 2 * DIM, g3, be3, pool, cnt);
    k_final<<<N_GRAPHS, DIM, 0, stream>>>(pool, cnt, fcW1, fcb1, fcW2, fcb2, out);
}